// Round 11
// baseline (196.394 us; speedup 1.0000x reference)
//
#include <hip/hip_runtime.h>
#include <hip/hip_bf16.h>
#include <math.h>

// Problem constants
#define BB 8
#define NN 1024
#define DD 512
#define HH 8
#define DHH 64
#define MLPD 2048

typedef __attribute__((ext_vector_type(8))) short short8;
typedef __attribute__((ext_vector_type(4))) float f32x4;

#define MFMA16(a,b,c) __builtin_amdgcn_mfma_f32_16x16x32_bf16(a,b,c,0,0,0)

// 0.125 * log2(e): folded softmax scale (applied to Q at QKV epilogue)
#define QSCALE 0.18033688011112042f
// bit pattern of -1e9f
#define NEGBIG 0xCE6E6B28u

__device__ __forceinline__ short f2bf(float f) {
  union { float f; unsigned u; } x; x.f = f;
  unsigned r = x.u + 0x7FFFu + ((x.u >> 16) & 1u);
  return (short)(r >> 16);
}

// async global->LDS, 16B per lane; LDS dest must be wave-uniform base
__device__ __forceinline__ void gl_lds16(const short* g, short* l) {
  __builtin_amdgcn_global_load_lds(
      (const __attribute__((address_space(1))) unsigned int*)g,
      (__attribute__((address_space(3))) unsigned int*)l, 16, 0, 0);
}

// fast gelu: tanh form, err <= ~1e-3 abs (output is bf16-rounded anyway;
// task threshold 20.48, so this is far below noise)
__device__ __forceinline__ float gelu_fast(float t) {
  const float u = 0.7978845608028654f * (t + 0.044715f * t * t * t);
  const float e = __builtin_amdgcn_exp2f(u * 2.8853900817779268f); // e^{2u}
  return t - t * __builtin_amdgcn_rcpf(e + 1.0f);                  // t*e/(e+1)
}

// ---------------- LayerNorm: f32 in -> bf16 out (+ optional f32 out) --------
template<bool WF32>
__global__ __launch_bounds__(256) void ln_kernel(const float* __restrict__ x,
    const float* __restrict__ gam, const float* __restrict__ bet,
    short* __restrict__ ob, float* __restrict__ of)
{
  const int row = blockIdx.x;
  const int tid = threadIdx.x;
  const float2 xv = *(const float2*)(x + (size_t)row*DD + tid*2);
  double s = (double)xv.x + (double)xv.y;
  for (int o = 32; o >= 1; o >>= 1) s += __shfl_down(s, o, 64);
  __shared__ double red[4];
  const int l = tid & 63, w = tid >> 6;
  if (l == 0) red[w] = s;
  __syncthreads();
  const double mu = (red[0]+red[1]+red[2]+red[3]) * (1.0/512.0);
  const double d0 = (double)xv.x - mu, d1 = (double)xv.y - mu;
  double q = d0*d0 + d1*d1;
  for (int o = 32; o >= 1; o >>= 1) q += __shfl_down(q, o, 64);
  __syncthreads();
  if (l == 0) red[w] = q;
  __syncthreads();
  const double var = (red[0]+red[1]+red[2]+red[3]) * (1.0/512.0);
  const float rs = (float)(1.0 / sqrt(var + 1e-5));
  const float mf = (float)mu;
  const float y0 = (xv.x - mf)*rs*gam[tid*2]   + bet[tid*2];
  const float y1 = (xv.y - mf)*rs*gam[tid*2+1] + bet[tid*2+1];
  ob[(size_t)row*DD + tid*2]   = f2bf(y0);
  ob[(size_t)row*DD + tid*2+1] = f2bf(y1);
  if (WF32) {
    of[(size_t)row*DD + tid*2]   = y0;
    of[(size_t)row*DD + tid*2+1] = y1;
  }
}

// ------- merged weight transpose + f32->bf16:  W[K][N] -> Wt[N][K] ---------
// one launch for all four weights; 1D grid of 3072 tile-blocks
__global__ __launch_bounds__(256) void wtall_kernel(
    const float* __restrict__ Wqkv, const float* __restrict__ Wout,
    const float* __restrict__ W1,   const float* __restrict__ W2,
    short* __restrict__ Wqkvt, short* __restrict__ Woutt,
    short* __restrict__ W1t,   short* __restrict__ W2t)
{
  const int id = blockIdx.x;
  const float* W; short* Wt; int K, N, t;
  if (id < 768)       { W = Wqkv; Wt = Wqkvt; K = 512;  N = 1536; t = id; }
  else if (id < 1024) { W = Wout; Wt = Woutt; K = 512;  N = 512;  t = id - 768; }
  else if (id < 2048) { W = W1;   Wt = W1t;   K = 512;  N = 2048; t = id - 1024; }
  else                { W = W2;   Wt = W2t;   K = 2048; N = 512;  t = id - 2048; }
  const int nx = N >> 5;
  const int n0 = (t % nx)*32, k0 = (t / nx)*32;
  __shared__ float tile[32][33];
  const int tx = threadIdx.x & 31, ty = threadIdx.x >> 5;  // ty 0..7
  #pragma unroll
  for (int j = 0; j < 4; j++)
    tile[ty + j*8][tx] = W[(size_t)(k0 + ty + j*8)*N + n0 + tx];
  __syncthreads();
  #pragma unroll
  for (int j = 0; j < 4; j++)
    Wt[(size_t)(n0 + ty + j*8)*K + k0 + tx] = f2bf(tile[tx][ty + j*8]);
}

// ---------------- mask -> bitfield:  maskbits[(b*N+q)*16 + kc] -------------
__global__ __launch_bounds__(256) void maskpack_kernel(const float* __restrict__ mask,
    unsigned long long* __restrict__ mb)
{
  const int wid = blockIdx.x*256 + threadIdx.x;   // 8192*16
  if (wid >= BB*NN*16) return;
  const int r = wid >> 4, c = wid & 15;
  const float4* p = (const float4*)(mask + (size_t)r*NN + c*64);
  unsigned long long m = 0;
  #pragma unroll
  for (int i = 0; i < 16; i++) {
    const float4 v = p[i];
    unsigned long long mm = 0;
    if (v.x == 1.0f) mm |= 1ULL;
    if (v.y == 1.0f) mm |= 2ULL;
    if (v.z == 1.0f) mm |= 4ULL;
    if (v.w == 1.0f) mm |= 8ULL;
    m |= mm << (i*4);
  }
  mb[wid] = m;
}

// ---------------- GEMM: A[M][K](bf16) x Bt[N][K](bf16) -> epilogues --------
// 128xBN tile, BK=32, 4 waves (2x2). NBUF=3: depth-2 pipeline, counted vmcnt.
// NBUF=2: 2-phase (catalog T3-minimum), 32KB LDS -> 4+ blocks/CU.
// LDS slot-swizzle (T2 via pre-swizzled global source, m173): physical slot
// (row, s) holds logical slot s ^ ((row>>1)&3) -> ds_read_b128 is 2-way (free).
// EPI 0: QKV scatter -> Qg(scaled)/Kg[bh][n][d], Vtg[bh][d][n]   (bf16)
// EPI 1: + bias[col] + res[row][col] -> f32 out
// EPI 2: + bias[col], fast gelu -> bf16 out
template<int BN, int EPI, int NBUF>
__global__ __launch_bounds__(256) void gemm_bt(
    const short* __restrict__ A, const short* __restrict__ Bt,
    int M, int N, int K,
    const float* __restrict__ bias, const float* __restrict__ res,
    float* __restrict__ outf, short* __restrict__ outb,
    short* __restrict__ outQ, short* __restrict__ outK, short* __restrict__ outVt)
{
  constexpr int CH = 8 + BN/16;          // 1KB chunks per K-tile (A:8, B:BN/16)
  constexpr int L  = CH/4;               // gl_lds per wave per tile (4 or 3)
  constexpr int BUFS = (128 + BN)*32;    // shorts per buffer
  __shared__ __align__(16) short lds[NBUF*BUFS];
  const int tid = threadIdx.x;
  const int bm0 = blockIdx.x * 128;
  const int bn0 = blockIdx.y * BN;
  const int lane = tid & 63, wid = tid >> 6;
  const int wm = (wid >> 1) * 64, wn = (wid & 1) * (BN/2);
  const int lr = lane & 15, lg = lane >> 4;
  constexpr int NT = BN/32;              // n-tiles of 16 per wave (4 or 2)

  // staging: chunk c = i*4 + wid; lane covers row c*16 + l/4, source slot
  // pre-swizzled so linear LDS ends up slot-XOR'd (involution per row)
  const short* gsrc[L];
  int loff[L];
  const int scc = (((lane & 3) ^ ((lane >> 3) & 3)))*8;   // pre-swizzled col
  #pragma unroll
  for (int i = 0; i < L; i++) {
    const int c = i*4 + wid;
    const int rr = ((c < 8) ? c : c - 8)*16 + (lane >> 2);
    gsrc[i] = (c < 8) ? (A + (size_t)(bm0 + rr)*K + scc)
                      : (Bt + (size_t)(bn0 + rr)*K + scc);
    loff[i] = c*512;                     // A at [0,4096), B at [4096,...)
  }
  const int xs = (lr >> 1) & 3;          // fragment-read slot XOR

  f32x4 acc[4][NT];
  #pragma unroll
  for (int i = 0; i < 4; i++)
    #pragma unroll
    for (int j = 0; j < NT; j++) acc[i][j] = f32x4{0.f,0.f,0.f,0.f};

  const int nsteps = K >> 5;

  auto STAGE = [&](int buf, int t) {
    short* dst = lds + buf*BUFS;
    const int ko = t*32;
    #pragma unroll
    for (int i = 0; i < L; i++)
      gl_lds16(gsrc[i] + ko, dst + loff[i]);
  };
  auto COMPUTE = [&](const short* bufA) {
    const short* bufB = bufA + 4096;
    short8 af[4], bfr[NT];
    #pragma unroll
    for (int mt = 0; mt < 4; mt++)
      af[mt] = *(const short8*)(bufA + (wm + mt*16 + lr)*32 + (lg ^ xs)*8);
    #pragma unroll
    for (int nt = 0; nt < NT; nt++)
      bfr[nt] = *(const short8*)(bufB + (wn + nt*16 + lr)*32 + (lg ^ xs)*8);
    __builtin_amdgcn_s_setprio(1);
    #pragma unroll
    for (int mt = 0; mt < 4; mt++)
      #pragma unroll
      for (int nt = 0; nt < NT; nt++)
        acc[mt][nt] = MFMA16(af[mt], bfr[nt], acc[mt][nt]);
    __builtin_amdgcn_s_setprio(0);
  };

  if constexpr (NBUF == 2) {
    // 2-phase: STAGE(t+1) || compute(t); vmcnt(0)+barrier per iter
    STAGE(0, 0);
    asm volatile("s_waitcnt vmcnt(0)" ::: "memory");
    __builtin_amdgcn_s_barrier();
    int cur = 0;
    #pragma unroll 1
    for (int t = 0; t < nsteps; t++) {
      if (t + 1 < nsteps) STAGE(cur ^ 1, t + 1);
      COMPUTE(lds + cur*BUFS);
      asm volatile("s_waitcnt vmcnt(0)" ::: "memory");
      __builtin_amdgcn_s_barrier();
      cur ^= 1;
    }
  } else {
    // depth-2: 3 buffers, counted vmcnt (loads span 2 iterations)
    STAGE(0, 0);
    STAGE(1, 1);
    int cur = 0;
    #pragma unroll 1
    for (int t = 0; t < nsteps; t++) {
      if (t == nsteps - 1) {
        asm volatile("s_waitcnt vmcnt(0)" ::: "memory");
      } else if constexpr (L == 4) {
        asm volatile("s_waitcnt vmcnt(4)" ::: "memory");
      } else {
        asm volatile("s_waitcnt vmcnt(3)" ::: "memory");
      }
      __builtin_amdgcn_s_barrier();
      if (t + 2 < nsteps) {
        const int bnext = (cur == 0) ? 2 : cur - 1;   // (cur+2)%3
        STAGE(bnext, t + 2);
      }
      COMPUTE(lds + cur*BUFS);
      cur = (cur == 2) ? 0 : cur + 1;
    }
  }

  if (EPI == 0 && bn0 >= 1024) {
    // V region: pack 4 consecutive tok into one 8B store to Vt[bh][d][tok]
    #pragma unroll
    for (int mt = 0; mt < 4; mt++)
      #pragma unroll
      for (int nt = 0; nt < NT; nt++) {
        const int row0 = bm0 + wm + mt*16 + lg*4;
        const int b = row0 >> 10, tok0 = row0 & 1023;
        const int c2 = bn0 + wn + nt*16 + lr - 1024;
        const int h = c2 >> 6, d = c2 & 63;
        unsigned lo2, hi2;
        asm("v_cvt_pk_bf16_f32 %0, %1, %2" : "=v"(lo2)
            : "v"(acc[mt][nt][0]), "v"(acc[mt][nt][1]));
        asm("v_cvt_pk_bf16_f32 %0, %1, %2" : "=v"(hi2)
            : "v"(acc[mt][nt][2]), "v"(acc[mt][nt][3]));
        uint2 pw; pw.x = lo2; pw.y = hi2;
        *(uint2*)(outVt + (((size_t)(b*HH + h))*DHH + d)*NN + tok0) = pw;
      }
    return;
  }

  #pragma unroll
  for (int mt = 0; mt < 4; mt++)
    #pragma unroll
    for (int nt = 0; nt < NT; nt++)
      #pragma unroll
      for (int r = 0; r < 4; r++) {
        const int row = bm0 + wm + mt*16 + lg*4 + r;
        const int col = bn0 + wn + nt*16 + lr;
        const float v = acc[mt][nt][r];
        if (EPI == 0) {
          const int b = row >> 10, tok = row & 1023;
          if (col < 512) {
            const int h = col >> 6, d = col & 63;
            outQ[(((size_t)(b*HH + h))*NN + tok)*DHH + d] = f2bf(v * QSCALE);
          } else {
            const int c2 = col - 512, h = c2 >> 6, d = c2 & 63;
            outK[(((size_t)(b*HH + h))*NN + tok)*DHH + d] = f2bf(v);
          }
        } else if (EPI == 1) {
          outf[(size_t)row*N + col] = v + bias[col] + res[(size_t)row*N + col];
        } else {
          outb[(size_t)row*N + col] = f2bf(gelu_fast(v + bias[col]));
        }
      }
}

// ---------------- flash attention (no-max), swapped QK^T, bit-mask --------
// grid 512 (XCD-swizzled: bh=(id&7)*8+((id>>3)&7), qb=id>>6) x 256 thr.
// K/V staged via global_load_lds into linear [64][64] LDS with unit-XOR
// swizzle (u_phys = u_log ^ (row&7)), pre-swizzled at the global source.
// S^T = mfma(K, Q); C-init = mask-bit * -1e9; p = exp2(s'); plain l-sum.
__global__ __launch_bounds__(256) void attn_kernel(
    const short* __restrict__ Qg, const short* __restrict__ Kg,
    const short* __restrict__ Vtg, const unsigned long long* __restrict__ mb,
    short* __restrict__ attout)
{
  const int id = blockIdx.x;
  const int bh = (id & 7)*8 + ((id >> 3) & 7);   // same-bh blocks -> same XCD
  const int qb = id >> 6;                        // 0..7
  const int b = bh >> 3, h = bh & 7;
  const int tid = threadIdx.x, lane = tid & 63, w = tid >> 6;
  const int lr = lane & 15, lg = lane >> 4;

  __shared__ __align__(16) short K0[64*64], K1[64*64];
  __shared__ __align__(16) short V0[64*64], V1[64*64];
  __shared__ __align__(16) short PsA[4][16*72], PsB[4][16*72];

  const int qA = qb*128 + w*32 + lr;          // set-A q-row for this lane
  const int qB = qA + 16;                     // set-B q-row
  short* PsAw = &PsA[w][0];
  short* PsBw = &PsB[w][0];

  // Q fragments (B operand); Q pre-scaled by QSCALE at the QKV epilogue
  const size_t qbase = (size_t)bh*NN*DHH;
  const short8 bqA0 = *(const short8*)(Qg + qbase + (size_t)qA*DHH + lg*8);
  const short8 bqA1 = *(const short8*)(Qg + qbase + (size_t)qA*DHH + 32 + lg*8);
  const short8 bqB0 = *(const short8*)(Qg + qbase + (size_t)qB*DHH + lg*8);
  const short8 bqB1 = *(const short8*)(Qg + qbase + (size_t)qB*DHH + 32 + lg*8);

  const unsigned long long* mrowA = mb + ((size_t)b*NN + qA)*16;
  const unsigned long long* mrowB = mb + ((size_t)b*NN + qB)*16;

  // gl_lds staging: wave w stages rows [w*16, w*16+16) of K and V chunks.
  // lane l -> local row l>>3, phys unit l&7; source holds logical unit
  // (l&7)^(l>>3)  (row&7 == l>>3 since bases are multiples of 8).
  const int l8 = lane >> 3;
  const int uu = (lane & 7) ^ l8;
  const short* kgA = Kg + ((size_t)bh*NN + w*16 + l8)*64 + uu*8;
  const short* kgB = kgA + 8*64;
  const short* vgA = Vtg + ((size_t)bh*DHH + w*16 + l8)*NN + uu*8;
  const short* vgB = vgA + 8*NN;
  auto STAGE = [&](short* kb, short* vb, int kc) {
    gl_lds16(kgA + kc*4096, kb + (w*16)*64);
    gl_lds16(kgB + kc*4096, kb + (w*16 + 8)*64);
    gl_lds16(vgA + kc*64,   vb + (w*16)*64);
    gl_lds16(vgB + kc*64,   vb + (w*16 + 8)*64);
  };
  // fragment-read unit offsets (shorts): logical lg and lg+4, XOR row&7
  const int xo0 = ((lg ^ (lr & 7)))*8;
  const int xo1 = (((lg ^ (lr & 7))) ^ 4)*8;

  unsigned long long mAc, mBc, mAn, mBn;

  // prologue: chunk 0 in flight
  STAGE(K0, V0, 0);
  mAc = mrowA[0]; mBc = mrowB[0];
  asm volatile("s_waitcnt vmcnt(0)" ::: "memory");
  __builtin_amdgcn_s_barrier();

  f32x4 oA[4], oB[4];
  #pragma unroll
  for (int dt = 0; dt < 4; dt++) { oA[dt] = f32x4{0.f,0.f,0.f,0.f}; oB[dt] = f32x4{0.f,0.f,0.f,0.f}; }
  float lsumA = 0.f, lsumB = 0.f;

#define ATT_BODY(CK, CV, NK, NV, MAc, MBc, MAn, MBn, KC, LAST)                 \
  {                                                                            \
    if (!(LAST)) {                                                             \
      STAGE(NK, NV, (KC)+1);                                                   \
      MAn = mrowA[(KC)+1]; MBn = mrowB[(KC)+1];                                \
    }                                                                          \
    /* C-init from mask bits: bit -> 0.0f or -1e9f */                          \
    f32x4 sA[4], sB[4];                                                        \
    {                                                                          \
      const unsigned long long mqA = MAc >> (lg*4);                            \
      const unsigned loA = (unsigned)mqA, hiA = (unsigned)(mqA >> 32);         \
      const unsigned long long mqB = MBc >> (lg*4);                            \
      const unsigned loB = (unsigned)mqB, hiB = (unsigned)(mqB >> 32);         \
      _Pragma("unroll")                                                        \
      for (int nt = 0; nt < 4; nt++) {                                         \
        const unsigned wA = (nt < 2) ? loA : hiA;                              \
        const unsigned wB = (nt < 2) ? loB : hiB;                              \
        const int sh = (nt & 1) * 16;                                          \
        _Pragma("unroll")                                                      \
        for (int rr = 0; rr < 4; rr++) {                                       \
          const unsigned bA = (wA >> (sh + rr)) & 1u;                          \
          const unsigned bB = (wB >> (sh + rr)) & 1u;                          \
          sA[nt][rr] = __uint_as_float((0u - bA) & NEGBIG);                    \
          sB[nt][rr] = __uint_as_float((0u - bB) & NEGBIG);                    \
        }                                                                      \
      }                                                                        \
    }                                                                          \
    __builtin_amdgcn_s_setprio(1);                                             \
    _Pragma("unroll")                                                          \
    for (int nt = 0; nt < 4; nt++) {                                           \
      const short* kr = (CK) + (nt*16 + lr)*64;                                \
      const short8 ak0 = *(const short8*)(kr + xo0);                           \
      const short8 ak1 = *(const short8*)(kr + xo1);                           \
      sA[nt] = MFMA16(ak0, bqA0, sA[nt]);                                      \
      sA[nt] = MFMA16(ak1, bqA1, sA[nt]);                                      \
      sB[nt] = MFMA16(ak0, bqB0, sB[nt]);                                      \
      sB[nt] = MFMA16(ak1, bqB1, sB[nt]);                                      \
    }                                                                          \
    __builtin_amdgcn_s_setprio(0);                                             \
    _Pragma("unroll")                                                          \
    for (int nt = 0; nt < 4; nt++) {                                           \
      const float a0 = __builtin_amdgcn_exp2f(sA[nt][0]);                      \
      const float a1 = __builtin_amdgcn_exp2f(sA[nt][1]);                      \
      const float a2 = __builtin_amdgcn_exp2f(sA[nt][2]);                      \
      const float a3 = __builtin_amdgcn_exp2f(sA[nt][3]);                      \
      lsumA += (a0 + a1) + (a2 + a3);                                          \
      unsigned plo, phi;                                                       \
      asm("v_cvt_pk_bf16_f32 %0, %1, %2" : "=v"(plo) : "v"(a0), "v"(a1));      \
      asm("v_cvt_pk_bf16_f32 %0, %1, %2" : "=v"(phi) : "v"(a2), "v"(a3));      \
      uint2 pw; pw.x = plo; pw.y = phi;                                        \
      *(uint2*)(PsAw + lr*72 + nt*16 + lg*4) = pw;                             \
      const float c0 = __builtin_amdgcn_exp2f(sB[nt][0]);                      \
      const float c1 = __builtin_amdgcn_exp2f(sB[nt][1]);                      \
      const float c2 = __builtin_amdgcn_exp2f(sB[nt][2]);                      \
      const float c3 = __builtin_amdgcn_exp2f(sB[nt][3]);                      \
      lsumB += (c0 + c1) + (c2 + c3);                                          \
      unsigned qlo, qhi;                                                       \
      asm("v_cvt_pk_bf16_f32 %0, %1, %2" : "=v"(qlo) : "v"(c0), "v"(c1));      \
      asm("v_cvt_pk_bf16_f32 %0, %1, %2" : "=v"(qhi) : "v"(c2), "v"(c3));      \
      uint2 qw; qw.x = qlo; qw.y = qhi;                                        \
      *(uint2*)(PsBw + lr*72 + nt*16 + lg*4) = qw;                             \
    }                                                                          \
    {                                                                          \
      const short8 bpA0 = *(const short8*)(PsAw + lr*72 + lg*8);               \
      const short8 bpA1 = *(const short8*)(PsAw + lr*72 + 32 + lg*8);          \
      const short8 bpB0 = *(const short8*)(PsBw + lr*72 + lg*8);               \
      const short8 bpB1 = *(const short8*)(PsBw + lr*72 + 32 + lg*8);          \
      __builtin_amdgcn_s_setprio(1);                                           \
      _Pragma("unroll")                                                        \
      for (int dt = 0; dt < 4; dt++) {                                         \
        const short* vr = (CV) + (dt*16 + lr)*64;                              \
        const short8 av0 = *(const short8*)(vr + xo0);                         \
        const short8 av1 = *(const short8*)(vr + xo1);                         \
        oA[dt] = MFMA16(av0, bpA0, oA[dt]);                                    \
        oA[dt] = MFMA16(av1, bpA1, oA[dt]);                                    \
        oB[dt] = MFMA16(av0, bpB0, oB[dt]);                                    \
        oB[dt] = MFMA16(av1, bpB1, oB[dt]);                                    \
      }                                                                        \
      __builtin_amdgcn_s_setprio(0);                                           \
    }                                                                          \
    if (!(LAST)) {                                                             \
      asm volatile("s_waitcnt vmcnt(0)" ::: "memory");                         \
      __builtin_amdgcn_s_barrier();                                            \
      MAc = MAn; MBc = MBn;                                                    \
    }                                                                          \
  }

  #pragma unroll 1
  for (int kc = 0; kc < 16; kc += 2) {
    ATT_BODY(K0, V0, K1, V1, mAc, mBc, mAn, mBn, kc, false)
    ATT_BODY(K1, V1, K0, V0, mAc, mBc, mAn, mBn, kc+1, (kc+1) == 15)
  }
#undef ATT_BODY

  // denominators: sum partials across the 4 lane-groups sharing q=lr
  lsumA += __shfl_xor(lsumA, 16, 64);
  lsumA += __shfl_xor(lsumA, 32, 64);
  lsumB += __shfl_xor(lsumB, 16, 64);
  lsumB += __shfl_xor(lsumB, 32, 64);
  const float linvA = 1.0f / lsumA;
  const float linvB = 1.0f / lsumB;

  // O^T -> per-wave LDS transpose, then coalesced 16B global stores
  #pragma unroll
  for (int dt = 0; dt < 4; dt++) {
    unsigned w0, w1, w2, w3;
    const float a0 = oA[dt][0]*linvA, a1 = oA[dt][1]*linvA;
    const float a2 = oA[dt][2]*linvA, a3 = oA[dt][3]*linvA;
    asm("v_cvt_pk_bf16_f32 %0, %1, %2" : "=v"(w0) : "v"(a0), "v"(a1));
    asm("v_cvt_pk_bf16_f32 %0, %1, %2" : "=v"(w1) : "v"(a2), "v"(a3));
    uint2 ow; ow.x = w0; ow.y = w1;
    *(uint2*)(PsAw + lr*72 + dt*16 + lg*4) = ow;
    const float c0 = oB[dt][0]*linvB, c1 = oB[dt][1]*linvB;
    const float c2 = oB[dt][2]*linvB, c3 = oB[dt][3]*linvB;
    asm("v_cvt_pk_bf16_f32 %0, %1, %2" : "=v"(w2) : "v"(c0), "v"(c1));
    asm("v_cvt_pk_bf16_f32 %0, %1, %2" : "=v"(w3) : "v"(c2), "v"(c3));
    uint2 ow2; ow2.x = w2; ow2.y = w3;
    *(uint2*)(PsBw + lr*72 + dt*16 + lg*4) = ow2;
  }
  #pragma unroll
  for (int rep = 0; rep < 2; rep++) {
    const int c = lane + rep*64;
    const int row = c >> 3, off = c & 7;
    const uint4 ovA = *(const uint4*)(PsAw + row*72 + off*8);
    *(uint4*)(attout + ((size_t)b*NN + qb*128 + w*32 + row)*DD + h*DHH + off*8) = ovA;
    const uint4 ovB = *(const uint4*)(PsBw + row*72 + off*8);
    *(uint4*)(attout + ((size_t)b*NN + qb*128 + w*32 + 16 + row)*DD + h*DHH + off*8) = ovB;
  }
}

// ---------------- exact score path (fp64) for what_to_prune ----------------
// fused q0 (LDS-only) + wv:  wv[bh][c] = sum_d q0[bh][d] * Wqkv[c][512+h*64+d]
__global__ __launch_bounds__(512) void q0wv_kernel(const float* __restrict__ hlnf,
    const float* __restrict__ Wqkv, double* __restrict__ wv)
{
  const int bh = blockIdx.x, b = bh >> 3, h = bh & 7;
  __shared__ double red[512];
  __shared__ double q0s[64];
  {
    const int d = threadIdx.x & 63, cg = threadIdx.x >> 6;   // 8 c-groups
    double acc = 0.0;
    #pragma unroll 8
    for (int c = cg*64; c < cg*64 + 64; c++)
      acc += (double)hlnf[(size_t)b*NN*DD + c] * (double)Wqkv[(size_t)c*1536 + h*64 + d];
    red[threadIdx.x] = acc;
    __syncthreads();
    if (threadIdx.x < 64) {
      double s = 0.0;
      #pragma unroll
      for (int g = 0; g < 8; g++) s += red[g*64 + d];
      q0s[d] = s;
    }
    __syncthreads();
  }
  const int c = threadIdx.x;
  const float4* wp = (const float4*)(Wqkv + (size_t)c*1536 + 512 + h*64);
  double acc = 0.0;
  #pragma unroll
  for (int dv = 0; dv < 16; dv++) {
    const float4 wq = wp[dv];
    acc += q0s[dv*4+0]*(double)wq.x + q0s[dv*4+1]*(double)wq.y
         + q0s[dv*4+2]*(double)wq.z + q0s[dv*4+3]*(double)wq.w;
  }
  wv[(size_t)bh*512 + c] = acc;
}

// srow[b][h][j] = sum_c hlnf[b][j][c] * wv[b][h][c]  (fp64)
// grid (8 b, 32 jc) x 256 thr = 32 j x 8 cg; c = cg*4 + 32*i (float4 chunks)
__global__ __launch_bounds__(256) void srow_kernel(const float* __restrict__ hlnf,
    const double* __restrict__ wv, const float* __restrict__ mask,
    double* __restrict__ srow)
{
  const int b = blockIdx.x, jc = blockIdx.y;       // jc 0..31
  const int jl = threadIdx.x >> 3;                 // 0..31
  const int cg = threadIdx.x & 7;                  // 0..7
  const int j  = jc*32 + jl;
  __shared__ double lw[8*512];                     // 32 KB
  __shared__ double red[32][8][9];                 // 18 KB (padded inner)
  for (int i = threadIdx.x; i < 4096; i += 256) lw[i] = wv[(size_t)b*4096 + i];
  __syncthreads();
  double acc[8] = {0,0,0,0,0,0,0,0};
  const float* xr = hlnf + ((size_t)b*NN + j)*DD;
  #pragma unroll
  for (int i = 0; i < 16; i++) {
    const int c = cg*4 + i*32;
    const float4 xv4 = *(const float4*)(xr + c);
    #pragma unroll
    for (int h = 0; h < 8; h++) {
      const double* lwc = lw + h*512 + c;
      acc[h] += (double)xv4.x*lwc[0] + (double)xv4.y*lwc[1]
              + (double)xv4.z*lwc[2] + (double)xv4.w*lwc[3];
    }
  }
  #pragma unroll
  for (int h = 0; h < 8; h++) red[jl][cg][h] = acc[h];
  __syncthreads();
  // 256 threads: one (j2, h2) pair each; sum the 8 c-group partials
  const int j2 = threadIdx.x >> 3, h2 = threadIdx.x & 7;
  double s = 0.0;
  #pragma unroll
  for (int g = 0; g < 8; g++) s += red[j2][g][h2];
  s *= 0.125;
  const float mval = mask[(size_t)b*NN*NN + jc*32 + j2];   // mask[b][0][j]
  if (mval == 1.0f) s = -1e10;
  srow[((size_t)b*8 + h2)*NN + jc*32 + j2] = s;
}

// fused denominator + att:  att[b][k] = mean_h exp(srow[h][k]) / sum_k' exp
// No max subtraction: srow is fp64 with |s| <~ 40 (scores are 0.125-scaled
// dots of LN'd activations with 0.02-scale weights), exp can't overflow;
// masked entries (-1e10) underflow to exactly 0, matching the reference
// denominator. Ratios identical to ~1e-15 — far beyond argsort gaps.
// grid 8 x 1024 thr; exps stored once in 64KB LDS, per-h tree reduce.
__global__ __launch_bounds__(1024) void sumatt_kernel(const double* __restrict__ srow,
    double* __restrict__ attv)
{
  const int b = blockIdx.x;
  const int t = threadIdx.x;
  __shared__ double e[8][1024];    // 64 KB
  __shared__ double red[1024];     // 8 KB
  __shared__ double sinv[8];
  const int h = t >> 7, j0 = t & 127;
  double ps = 0.0;
  #pragma unroll
  for (int i = 0; i < 8; i++) {
    const int j = j0 + i*128;
    const double v = exp(srow[((size_t)b*8 + h)*NN + j]);
    e[h][j] = v;
    ps += v;
  }
  red[t] = ps;
  __syncthreads();
  #pragma unroll
  for (int off = 64; off >= 1; off >>= 1) {
    if (j0 < off) red[t] += red[t + off];
    __syncthreads();
  }
  if (j0 == 0) sinv[h] = 1.0 / red[t];
  __syncthreads();
  double s = 0.0;
  #pragma unroll
  for (int hh = 0; hh < 8; hh++) s += e[hh][t] * sinv[hh];
  attv[b*NN + t] = (t == 0) ? -INFINITY : s * 0.125;
}

// rank-by-counting (exact stable-argsort semantics), parallelized:
// grid (8 b, 32 jc) x 256 thr; 8 threads per j, 128 k's each, LDS reduce.
// Per-kg index rotation (i + kg*2) & 127 spreads the 8 concurrent LDS
// addresses across distinct bank pairs (conflict-free; same-addr = bcast).
__global__ __launch_bounds__(256) void rank_kernel(const double* __restrict__ attv,
    float* __restrict__ dout, int offP, int offM, int offS)
{
  const int b = blockIdx.x, jc = blockIdx.y;
  const int t = threadIdx.x;
  __shared__ double a[1024];
  __shared__ int red[32][8];
  #pragma unroll
  for (int rep = 0; rep < 4; rep++)
    a[rep*256 + t] = attv[b*NN + rep*256 + t];
  __syncthreads();
  const int jl = t >> 3, kg = t & 7;
  const int j = jc*32 + jl;
  const double aj = a[j];
  int r = 0;
  #pragma unroll 8
  for (int i = 0; i < 128; i++) {
    const int idx = kg*128 + ((i + kg*2) & 127);
    const double ak = a[idx];
    r += ((ak > aj) || (ak == aj && idx < j)) ? 1 : 0;
  }
  red[jl][kg] = r;
  __syncthreads();
  if (t < 32) {
    int rr = 0;
    #pragma unroll
    for (int g = 0; g < 8; g++) rr += red[t][g];
    const int jj = jc*32 + t;
    if (rr >= 959 && rr <= 1022) dout[offP + b*64 + (rr - 959)] = (float)jj;
  }
  if (b == 0 && jc == 0) {
    if (t < 8)   dout[offM + t] = -1.0f;
    if (t < 128) dout[offS + t] = 0.0f;
  }
}

// ---------------------------------------------------------------------------
extern "C" void kernel_launch(void* const* d_in, const int* in_sizes, int n_in,
                              void* d_out, int out_size, void* d_ws, size_t ws_size,
                              hipStream_t stream) {
  (void)in_sizes; (void)n_in; (void)out_size; (void)ws_size;
  const float* x     = (const float*)d_in[0];
  const float* mask  = (const float*)d_in[1];
  const float* Wqkv  = (const float*)d_in[2];
  const float* Wout  = (const float*)d_in[3];
  const float* bout  = (const float*)d_in[4];
  const float* ln1g  = (const float*)d_in[5];
  const float* ln1b  = (const float*)d_in[6];
  const float* ln2g  = (const float*)d_in[7];
  const float* ln2b  = (const float*)d_in[8];
  const float* W1    = (const float*)d_in[9];
  const float* b1    = (const float*)d_in[10];
  const float* W2    = (const float*)d_in[11];
  const float* b2    = (const float*)d_in[12];
  float* dout = (float*)d_out;

  const size_t MB = 1ull << 20;
  char* ws = (char*)d_ws;
  short*  hln_bf = (short*)(ws + 0);           // 8 MB
  float*  hlnf   = (float*)(ws + 8*MB);        // 16 MB
  short*  Qg     = (short*)(ws + 24*MB);       // 8 MB
  short*  Kg     = (short*)(ws + 32*MB);       // 8 MB
  short*  Vtg    = (short*)(ws + 40*MB);       // 8 MB
  unsigned long long* mbits = (unsigned long long*)(ws + 48*MB); // 1 MB
  short*  Wqkvt  = (short*)(ws + 49*MB);       // 1.5 MB
  short*  Woutt  = (short*)(ws + 51*MB);       // 0.5 MB
  short*  W1t    = (short*)(ws + 52*MB);       // 2 MB
  short*  W2t    = (short*)(ws + 54*MB);       // 2 MB
  double* wvv    = (double*)(ws + 56*MB + 256*1024);   // 256 KB
  double* srow   = (double*)(ws + 57*MB);              // 512 KB
  double* attv   = (double*)(ws + 59*MB);              // 64 KB
  short*  attout = (short*)(ws + 60*MB);       // 8 MB
  float*  x1     = (float*)(ws + 68*MB);       // 16 MB
  short*  h2     = (short*)(ws + 84*MB);       // 8 MB
  short*  gbuf   = (short*)(ws + 0);           // 32 MB, reuses [0,32) (dead by MLP1)

  const int offP = BB*NN*DD;          // 4194304
  const int offM = offP + BB*64;      // 4194816
  const int offS = offM + BB;         // 4194824

  // 1) LN1 (bf16 + f32 copies)
  ln_kernel<true><<<BB*NN, 256, 0, stream>>>(x, ln1g, ln1b, hln_bf, hlnf);

  // 2) exact fp64 score path -> what_to_prune (+ constant tails)
  q0wv_kernel<<<BB*HH, 512, 0, stream>>>(hlnf, Wqkv, wvv);
  srow_kernel<<<dim3(BB, 32), 256, 0, stream>>>(hlnf, wvv, mask, srow);
  sumatt_kernel<<<BB, 1024, 0, stream>>>(srow, attv);
  rank_kernel<<<dim3(BB, 32), 256, 0, stream>>>(attv, dout, offP, offM, offS);

  // 3) mask bitfield + merged weight transposes
  maskpack_kernel<<<(BB*NN*16)/256, 256, 0, stream>>>(mask, mbits);
  wtall_kernel<<<3072, 256, 0, stream>>>(Wqkv, Wout, W1, W2,
      Wqkvt, Woutt, W1t, W2t);

  // 4) QKV projection (768 blocks = 3/CU uniform; depth-2)
  gemm_bt<128,0,3><<<dim3(64, 12), 256, 0, stream>>>(hln_bf, Wqkvt, BB*NN, 1536, 512,
      nullptr, nullptr, nullptr, nullptr, Qg, Kg, Vtg);

  // 5) flash attention (XCD-swizzled grid; gl_lds K/V staging)
  attn_kernel<<<512, 256, 0, stream>>>(Qg, Kg, Vtg, mbits, attout);

  // 6) out-proj + bias + residual -> x1 (f32); 512 blocks = 2/CU, depth-2
  gemm_bt<64,1,3><<<dim3(64, 8), 256, 0, stream>>>(attout, Woutt, BB*NN, 512, 512,
      bout, x, x1, nullptr, nullptr, nullptr, nullptr);

  // 7) LN2
  ln_kernel<false><<<BB*NN, 256, 0, stream>>>(x1, ln2g, ln2b, h2, nullptr);

  // 8) MLP1 + gelu -> gbuf; BN=64 depth-2 counted (36KB -> 4/CU, 2048 blocks
  //    = two uniform rounds); replaces the vmcnt(0)-drain 2-phase
  gemm_bt<64,2,3><<<dim3(64, 32), 256, 0, stream>>>(h2, W1t, BB*NN, 2048, 512,
      b1, nullptr, nullptr, gbuf, nullptr, nullptr, nullptr);

  // 9) MLP2 + bias + residual -> final x (f32); 512 blocks = 2/CU, depth-2
  gemm_bt<64,1,3><<<dim3(64, 8), 256, 0, stream>>>(gbuf, W2t, BB*NN, 512, 2048,
      b2, x1, dout, nullptr, nullptr, nullptr, nullptr);
}

// Round 12
// 189.114 us; speedup vs baseline: 1.0385x; 1.0385x over previous
//
#include <hip/hip_runtime.h>
#include <hip/hip_bf16.h>
#include <math.h>

// Problem constants
#define BB 8
#define NN 1024
#define DD 512
#define HH 8
#define DHH 64
#define MLPD 2048

typedef __attribute__((ext_vector_type(8))) short short8;
typedef __attribute__((ext_vector_type(4))) float f32x4;

#define MFMA16(a,b,c) __builtin_amdgcn_mfma_f32_16x16x32_bf16(a,b,c,0,0,0)

// 0.125 * log2(e): folded softmax scale (applied to Q at QKV epilogue)
#define QSCALE 0.18033688011112042f
// bit pattern of -1e9f
#define NEGBIG 0xCE6E6B28u

__device__ __forceinline__ short f2bf(float f) {
  union { float f; unsigned u; } x; x.f = f;
  unsigned r = x.u + 0x7FFFu + ((x.u >> 16) & 1u);
  return (short)(r >> 16);
}
__device__ __forceinline__ float bf2f(short s) {
  union { float f; unsigned u; } x;
  x.u = ((unsigned)(unsigned short)s) << 16;
  return x.f;
}

// async global->LDS, 16B per lane; LDS dest must be wave-uniform base
__device__ __forceinline__ void gl_lds16(const short* g, short* l) {
  __builtin_amdgcn_global_load_lds(
      (const __attribute__((address_space(1))) unsigned int*)g,
      (__attribute__((address_space(3))) unsigned int*)l, 16, 0, 0);
}

// fast gelu: tanh form, err <= ~1e-3 abs
__device__ __forceinline__ float gelu_fast(float t) {
  const float u = 0.7978845608028654f * (t + 0.044715f * t * t * t);
  const float e = __builtin_amdgcn_exp2f(u * 2.8853900817779268f); // e^{2u}
  return t - t * __builtin_amdgcn_rcpf(e + 1.0f);                  // t*e/(e+1)
}

// ------- merged prep: LN1 (blocks 0..8191) + maskpack (8192..8703) +
//         weight transpose x4 (8704..11775) ------------------------------
__global__ __launch_bounds__(256) void prep_kernel(
    const float* __restrict__ x, const float* __restrict__ ln1g,
    const float* __restrict__ ln1b, short* __restrict__ hln_bf,
    float* __restrict__ hlnf,
    const float* __restrict__ mask, unsigned long long* __restrict__ mbits,
    const float* __restrict__ Wqkv, const float* __restrict__ Wout,
    const float* __restrict__ W1,   const float* __restrict__ W2,
    short* __restrict__ Wqkvt, short* __restrict__ Woutt,
    short* __restrict__ W1t,   short* __restrict__ W2t)
{
  const int id = blockIdx.x;
  const int tid = threadIdx.x;
  if (id < 8192) {
    // ---- LN1: f32 in -> bf16 out + f32 out ----
    __shared__ double red[4];
    const int row = id;
    const float2 xv = *(const float2*)(x + (size_t)row*DD + tid*2);
    double s = (double)xv.x + (double)xv.y;
    for (int o = 32; o >= 1; o >>= 1) s += __shfl_down(s, o, 64);
    const int l = tid & 63, w = tid >> 6;
    if (l == 0) red[w] = s;
    __syncthreads();
    const double mu = (red[0]+red[1]+red[2]+red[3]) * (1.0/512.0);
    const double d0 = (double)xv.x - mu, d1 = (double)xv.y - mu;
    double q = d0*d0 + d1*d1;
    for (int o = 32; o >= 1; o >>= 1) q += __shfl_down(q, o, 64);
    __syncthreads();
    if (l == 0) red[w] = q;
    __syncthreads();
    const double var = (red[0]+red[1]+red[2]+red[3]) * (1.0/512.0);
    const float rs = (float)(1.0 / sqrt(var + 1e-5));
    const float mf = (float)mu;
    const float y0 = (xv.x - mf)*rs*ln1g[tid*2]   + ln1b[tid*2];
    const float y1 = (xv.y - mf)*rs*ln1g[tid*2+1] + ln1b[tid*2+1];
    hln_bf[(size_t)row*DD + tid*2]   = f2bf(y0);
    hln_bf[(size_t)row*DD + tid*2+1] = f2bf(y1);
    hlnf[(size_t)row*DD + tid*2]   = y0;
    hlnf[(size_t)row*DD + tid*2+1] = y1;
  } else if (id < 8704) {
    // ---- mask -> bitfield ----
    const int wid = (id - 8192)*256 + tid;
    const int r = wid >> 4, c = wid & 15;
    const float4* p = (const float4*)(mask + (size_t)r*NN + c*64);
    unsigned long long m = 0;
    #pragma unroll
    for (int i = 0; i < 16; i++) {
      const float4 v = p[i];
      unsigned long long mm = 0;
      if (v.x == 1.0f) mm |= 1ULL;
      if (v.y == 1.0f) mm |= 2ULL;
      if (v.z == 1.0f) mm |= 4ULL;
      if (v.w == 1.0f) mm |= 8ULL;
      m |= mm << (i*4);
    }
    mbits[wid] = m;
  } else {
    // ---- weight transpose + f32->bf16 ----
    const int id2 = id - 8704;
    const float* W; short* Wt; int K, N, t;
    if (id2 < 768)       { W = Wqkv; Wt = Wqkvt; K = 512;  N = 1536; t = id2; }
    else if (id2 < 1024) { W = Wout; Wt = Woutt; K = 512;  N = 512;  t = id2 - 768; }
    else if (id2 < 2048) { W = W1;   Wt = W1t;   K = 512;  N = 2048; t = id2 - 1024; }
    else                 { W = W2;   Wt = W2t;   K = 2048; N = 512;  t = id2 - 2048; }
    const int nx = N >> 5;
    const int n0 = (t % nx)*32, k0 = (t / nx)*32;
    __shared__ float tile[32][33];
    const int tx = tid & 31, ty = tid >> 5;
    #pragma unroll
    for (int j = 0; j < 4; j++)
      tile[ty + j*8][tx] = W[(size_t)(k0 + ty + j*8)*N + n0 + tx];
    __syncthreads();
    #pragma unroll
    for (int j = 0; j < 4; j++)
      Wt[(size_t)(n0 + ty + j*8)*K + k0 + tx] = f2bf(tile[tx][ty + j*8]);
  }
}

// ---------------- LN2: bf16 in -> bf16 out ---------------------------------
__global__ __launch_bounds__(256) void ln2_kernel(const short* __restrict__ xb,
    const float* __restrict__ gam, const float* __restrict__ bet,
    short* __restrict__ ob)
{
  const int row = blockIdx.x;
  const int tid = threadIdx.x;
  const short2 xs = *(const short2*)(xb + (size_t)row*DD + tid*2);
  const float x0 = bf2f(xs.x), x1v = bf2f(xs.y);
  double s = (double)x0 + (double)x1v;
  for (int o = 32; o >= 1; o >>= 1) s += __shfl_down(s, o, 64);
  __shared__ double red[4];
  const int l = tid & 63, w = tid >> 6;
  if (l == 0) red[w] = s;
  __syncthreads();
  const double mu = (red[0]+red[1]+red[2]+red[3]) * (1.0/512.0);
  const double d0 = (double)x0 - mu, d1 = (double)x1v - mu;
  double q = d0*d0 + d1*d1;
  for (int o = 32; o >= 1; o >>= 1) q += __shfl_down(q, o, 64);
  __syncthreads();
  if (l == 0) red[w] = q;
  __syncthreads();
  const double var = (red[0]+red[1]+red[2]+red[3]) * (1.0/512.0);
  const float rs = (float)(1.0 / sqrt(var + 1e-5));
  const float mf = (float)mu;
  ob[(size_t)row*DD + tid*2]   = f2bf((x0  - mf)*rs*gam[tid*2]   + bet[tid*2]);
  ob[(size_t)row*DD + tid*2+1] = f2bf((x1v - mf)*rs*gam[tid*2+1] + bet[tid*2+1]);
}

// ---------------- GEMM: A[M][K](bf16) x Bt[N][K](bf16) -> epilogues --------
// 128xBN tile, BK=32, 4 waves (2x2). NBUF=3: depth-2, counted vmcnt.
// NBUF=2: 2-phase, 32KB LDS -> 4+ blocks/CU.
// EPI 0: QKV scatter -> Qg(scaled)/Kg[bh][n][d], Vtg[bh][d][n]   (bf16)
// EPI 2: + bias[col], fast gelu -> bf16 out
// EPI 3: + bias[col] + res_f32[row][col] -> bf16 out   (outproj -> x1b)
// EPI 4: + bias[col] + res_bf16[row][col] -> f32 out   (MLP2 -> dout)
template<int BN, int EPI, int NBUF>
__global__ __launch_bounds__(256) void gemm_bt(
    const short* __restrict__ A, const short* __restrict__ Bt,
    int M, int N, int K,
    const float* __restrict__ bias, const float* __restrict__ res,
    const short* __restrict__ resb,
    float* __restrict__ outf, short* __restrict__ outb,
    short* __restrict__ outQ, short* __restrict__ outK, short* __restrict__ outVt)
{
  constexpr int CH = 8 + BN/16;          // 1KB chunks per K-tile (A:8, B:BN/16)
  constexpr int L  = CH/4;               // gl_lds per wave per tile (4 or 3)
  constexpr int BUFS = (128 + BN)*32;    // shorts per buffer
  __shared__ __align__(16) short lds[NBUF*BUFS];
  const int tid = threadIdx.x;
  const int bm0 = blockIdx.x * 128;
  const int bn0 = blockIdx.y * BN;
  const int lane = tid & 63, wid = tid >> 6;
  const int wm = (wid >> 1) * 64, wn = (wid & 1) * (BN/2);
  const int lr = lane & 15, lg = lane >> 4;
  constexpr int NT = BN/32;              // n-tiles of 16 per wave (4 or 2)

  const short* gsrc[L];
  int loff[L];
  const int scc = (((lane & 3) ^ ((lane >> 3) & 3)))*8;   // pre-swizzled col
  #pragma unroll
  for (int i = 0; i < L; i++) {
    const int c = i*4 + wid;
    const int rr = ((c < 8) ? c : c - 8)*16 + (lane >> 2);
    gsrc[i] = (c < 8) ? (A + (size_t)(bm0 + rr)*K + scc)
                      : (Bt + (size_t)(bn0 + rr)*K + scc);
    loff[i] = c*512;
  }
  const int xs = (lr >> 1) & 3;          // fragment-read slot XOR

  f32x4 acc[4][NT];
  #pragma unroll
  for (int i = 0; i < 4; i++)
    #pragma unroll
    for (int j = 0; j < NT; j++) acc[i][j] = f32x4{0.f,0.f,0.f,0.f};

  const int nsteps = K >> 5;

  auto STAGE = [&](int buf, int t) {
    short* dst = lds + buf*BUFS;
    const int ko = t*32;
    #pragma unroll
    for (int i = 0; i < L; i++)
      gl_lds16(gsrc[i] + ko, dst + loff[i]);
  };
  auto COMPUTE = [&](const short* bufA) {
    const short* bufB = bufA + 4096;
    short8 af[4], bfr[NT];
    #pragma unroll
    for (int mt = 0; mt < 4; mt++)
      af[mt] = *(const short8*)(bufA + (wm + mt*16 + lr)*32 + (lg ^ xs)*8);
    #pragma unroll
    for (int nt = 0; nt < NT; nt++)
      bfr[nt] = *(const short8*)(bufB + (wn + nt*16 + lr)*32 + (lg ^ xs)*8);
    __builtin_amdgcn_s_setprio(1);
    #pragma unroll
    for (int mt = 0; mt < 4; mt++)
      #pragma unroll
      for (int nt = 0; nt < NT; nt++)
        acc[mt][nt] = MFMA16(af[mt], bfr[nt], acc[mt][nt]);
    __builtin_amdgcn_s_setprio(0);
  };

  if constexpr (NBUF == 2) {
    STAGE(0, 0);
    asm volatile("s_waitcnt vmcnt(0)" ::: "memory");
    __builtin_amdgcn_s_barrier();
    int cur = 0;
    #pragma unroll 1
    for (int t = 0; t < nsteps; t++) {
      if (t + 1 < nsteps) STAGE(cur ^ 1, t + 1);
      COMPUTE(lds + cur*BUFS);
      asm volatile("s_waitcnt vmcnt(0)" ::: "memory");
      __builtin_amdgcn_s_barrier();
      cur ^= 1;
    }
  } else {
    STAGE(0, 0);
    STAGE(1, 1);
    int cur = 0;
    #pragma unroll 1
    for (int t = 0; t < nsteps; t++) {
      if (t == nsteps - 1) {
        asm volatile("s_waitcnt vmcnt(0)" ::: "memory");
      } else if constexpr (L == 4) {
        asm volatile("s_waitcnt vmcnt(4)" ::: "memory");
      } else {
        asm volatile("s_waitcnt vmcnt(3)" ::: "memory");
      }
      __builtin_amdgcn_s_barrier();
      if (t + 2 < nsteps) {
        const int bnext = (cur == 0) ? 2 : cur - 1;   // (cur+2)%3
        STAGE(bnext, t + 2);
      }
      COMPUTE(lds + cur*BUFS);
      cur = (cur == 2) ? 0 : cur + 1;
    }
  }

  if (EPI == 0 && bn0 >= 1024) {
    #pragma unroll
    for (int mt = 0; mt < 4; mt++)
      #pragma unroll
      for (int nt = 0; nt < NT; nt++) {
        const int row0 = bm0 + wm + mt*16 + lg*4;
        const int b = row0 >> 10, tok0 = row0 & 1023;
        const int c2 = bn0 + wn + nt*16 + lr - 1024;
        const int h = c2 >> 6, d = c2 & 63;
        unsigned lo2, hi2;
        asm("v_cvt_pk_bf16_f32 %0, %1, %2" : "=v"(lo2)
            : "v"(acc[mt][nt][0]), "v"(acc[mt][nt][1]));
        asm("v_cvt_pk_bf16_f32 %0, %1, %2" : "=v"(hi2)
            : "v"(acc[mt][nt][2]), "v"(acc[mt][nt][3]));
        uint2 pw; pw.x = lo2; pw.y = hi2;
        *(uint2*)(outVt + (((size_t)(b*HH + h))*DHH + d)*NN + tok0) = pw;
      }
    return;
  }

  #pragma unroll
  for (int mt = 0; mt < 4; mt++)
    #pragma unroll
    for (int nt = 0; nt < NT; nt++)
      #pragma unroll
      for (int r = 0; r < 4; r++) {
        const int row = bm0 + wm + mt*16 + lg*4 + r;
        const int col = bn0 + wn + nt*16 + lr;
        const float v = acc[mt][nt][r];
        if (EPI == 0) {
          const int b = row >> 10, tok = row & 1023;
          if (col < 512) {
            const int h = col >> 6, d = col & 63;
            outQ[(((size_t)(b*HH + h))*NN + tok)*DHH + d] = f2bf(v * QSCALE);
          } else {
            const int c2 = col - 512, h = c2 >> 6, d = c2 & 63;
            outK[(((size_t)(b*HH + h))*NN + tok)*DHH + d] = f2bf(v);
          }
        } else if (EPI == 2) {
          outb[(size_t)row*N + col] = f2bf(gelu_fast(v + bias[col]));
        } else if (EPI == 3) {
          outb[(size_t)row*N + col] = f2bf(v + bias[col] + res[(size_t)row*N + col]);
        } else {  // EPI 4
          outf[(size_t)row*N + col] = v + bias[col] + bf2f(resb[(size_t)row*N + col]);
        }
      }
}

// ---------------- flash attention (no-max), swapped QK^T, bit-mask --------
__global__ __launch_bounds__(256) void attn_kernel(
    const short* __restrict__ Qg, const short* __restrict__ Kg,
    const short* __restrict__ Vtg, const unsigned long long* __restrict__ mb,
    short* __restrict__ attout)
{
  const int id = blockIdx.x;
  const int bh = (id & 7)*8 + ((id >> 3) & 7);   // same-bh blocks -> same XCD
  const int qb = id >> 6;                        // 0..7
  const int b = bh >> 3, h = bh & 7;
  const int tid = threadIdx.x, lane = tid & 63, w = tid >> 6;
  const int lr = lane & 15, lg = lane >> 4;

  __shared__ __align__(16) short K0[64*64], K1[64*64];
  __shared__ __align__(16) short V0[64*64], V1[64*64];
  __shared__ __align__(16) short PsA[4][16*72], PsB[4][16*72];

  const int qA = qb*128 + w*32 + lr;
  const int qB = qA + 16;
  short* PsAw = &PsA[w][0];
  short* PsBw = &PsB[w][0];

  const size_t qbase = (size_t)bh*NN*DHH;
  const short8 bqA0 = *(const short8*)(Qg + qbase + (size_t)qA*DHH + lg*8);
  const short8 bqA1 = *(const short8*)(Qg + qbase + (size_t)qA*DHH + 32 + lg*8);
  const short8 bqB0 = *(const short8*)(Qg + qbase + (size_t)qB*DHH + lg*8);
  const short8 bqB1 = *(const short8*)(Qg + qbase + (size_t)qB*DHH + 32 + lg*8);

  const unsigned long long* mrowA = mb + ((size_t)b*NN + qA)*16;
  const unsigned long long* mrowB = mb + ((size_t)b*NN + qB)*16;

  const int l8 = lane >> 3;
  const int uu = (lane & 7) ^ l8;
  const short* kgA = Kg + ((size_t)bh*NN + w*16 + l8)*64 + uu*8;
  const short* kgB = kgA + 8*64;
  const short* vgA = Vtg + ((size_t)bh*DHH + w*16 + l8)*NN + uu*8;
  const short* vgB = vgA + 8*NN;
  auto STAGE = [&](short* kb, short* vb, int kc) {
    gl_lds16(kgA + kc*4096, kb + (w*16)*64);
    gl_lds16(kgB + kc*4096, kb + (w*16 + 8)*64);
    gl_lds16(vgA + kc*64,   vb + (w*16)*64);
    gl_lds16(vgB + kc*64,   vb + (w*16 + 8)*64);
  };
  const int xo0 = ((lg ^ (lr & 7)))*8;
  const int xo1 = (((lg ^ (lr & 7))) ^ 4)*8;

  unsigned long long mAc, mBc, mAn, mBn;

  STAGE(K0, V0, 0);
  mAc = mrowA[0]; mBc = mrowB[0];
  asm volatile("s_waitcnt vmcnt(0)" ::: "memory");
  __builtin_amdgcn_s_barrier();

  f32x4 oA[4], oB[4];
  #pragma unroll
  for (int dt = 0; dt < 4; dt++) { oA[dt] = f32x4{0.f,0.f,0.f,0.f}; oB[dt] = f32x4{0.f,0.f,0.f,0.f}; }
  float lsumA = 0.f, lsumB = 0.f;

#define ATT_BODY(CK, CV, NK, NV, MAc, MBc, MAn, MBn, KC, LAST)                 \
  {                                                                            \
    if (!(LAST)) {                                                             \
      STAGE(NK, NV, (KC)+1);                                                   \
      MAn = mrowA[(KC)+1]; MBn = mrowB[(KC)+1];                                \
    }                                                                          \
    f32x4 sA[4], sB[4];                                                        \
    {                                                                          \
      const unsigned long long mqA = MAc >> (lg*4);                            \
      const unsigned loA = (unsigned)mqA, hiA = (unsigned)(mqA >> 32);         \
      const unsigned long long mqB = MBc >> (lg*4);                            \
      const unsigned loB = (unsigned)mqB, hiB = (unsigned)(mqB >> 32);         \
      _Pragma("unroll")                                                        \
      for (int nt = 0; nt < 4; nt++) {                                         \
        const unsigned wA = (nt < 2) ? loA : hiA;                              \
        const unsigned wB = (nt < 2) ? loB : hiB;                              \
        const int sh = (nt & 1) * 16;                                          \
        _Pragma("unroll")                                                      \
        for (int rr = 0; rr < 4; rr++) {                                       \
          const unsigned bA = (wA >> (sh + rr)) & 1u;                          \
          const unsigned bB = (wB >> (sh + rr)) & 1u;                          \
          sA[nt][rr] = __uint_as_float((0u - bA) & NEGBIG);                    \
          sB[nt][rr] = __uint_as_float((0u - bB) & NEGBIG);                    \
        }                                                                      \
      }                                                                        \
    }                                                                          \
    __builtin_amdgcn_s_setprio(1);                                             \
    _Pragma("unroll")                                                          \
    for (int nt = 0; nt < 4; nt++) {                                           \
      const short* kr = (CK) + (nt*16 + lr)*64;                                \
      const short8 ak0 = *(const short8*)(kr + xo0);                           \
      const short8 ak1 = *(const short8*)(kr + xo1);                           \
      sA[nt] = MFMA16(ak0, bqA0, sA[nt]);                                      \
      sA[nt] = MFMA16(ak1, bqA1, sA[nt]);                                      \
      sB[nt] = MFMA16(ak0, bqB0, sB[nt]);                                      \
      sB[nt] = MFMA16(ak1, bqB1, sB[nt]);                                      \
    }                                                                          \
    __builtin_amdgcn_s_setprio(0);                                             \
    _Pragma("unroll")                                                          \
    for (int nt = 0; nt < 4; nt++) {                                           \
      const float a0 = __builtin_amdgcn_exp2f(sA[nt][0]);                      \
      const float a1 = __builtin_amdgcn_exp2f(sA[nt][1]);                      \
      const float a2 = __builtin_amdgcn_exp2f(sA[nt][2]);                      \
      const float a3 = __builtin_amdgcn_exp2f(sA[nt][3]);                      \
      lsumA += (a0 + a1) + (a2 + a3);                                          \
      unsigned plo, phi;                                                       \
      asm("v_cvt_pk_bf16_f32 %0, %1, %2" : "=v"(plo) : "v"(a0), "v"(a1));      \
      asm("v_cvt_pk_bf16_f32 %0, %1, %2" : "=v"(phi) : "v"(a2), "v"(a3));      \
      uint2 pw; pw.x = plo; pw.y = phi;                                        \
      *(uint2*)(PsAw + lr*72 + nt*16 + lg*4) = pw;                             \
      const float c0 = __builtin_amdgcn_exp2f(sB[nt][0]);                      \
      const float c1 = __builtin_amdgcn_exp2f(sB[nt][1]);                      \
      const float c2 = __builtin_amdgcn_exp2f(sB[nt][2]);                      \
      const float c3 = __builtin_amdgcn_exp2f(sB[nt][3]);                      \
      lsumB += (c0 + c1) + (c2 + c3);                                          \
      unsigned qlo, qhi;                                                       \
      asm("v_cvt_pk_bf16_f32 %0, %1, %2" : "=v"(qlo) : "v"(c0), "v"(c1));      \
      asm("v_cvt_pk_bf16_f32 %0, %1, %2" : "=v"(qhi) : "v"(c2), "v"(c3));      \
      uint2 qw; qw.x = qlo; qw.y = qhi;                                        \
      *(uint2*)(PsBw + lr*72 + nt*16 + lg*4) = qw;                             \
    }                                                                          \
    {                                                                          \
      const short8 bpA0 = *(const short8*)(PsAw + lr*72 + lg*8);               \
      const short8 bpA1 = *(const short8*)(PsAw + lr*72 + 32 + lg*8);          \
      const short8 bpB0 = *(const short8*)(PsBw + lr*72 + lg*8);               \
      const short8 bpB1 = *(const short8*)(PsBw + lr*72 + 32 + lg*8);          \
      __builtin_amdgcn_s_setprio(1);                                           \
      _Pragma("unroll")                                                        \
      for (int dt = 0; dt < 4; dt++) {                                         \
        const short* vr = (CV) + (dt*16 + lr)*64;                              \
        const short8 av0 = *(const short8*)(vr + xo0);                         \
        const short8 av1 = *(const short8*)(vr + xo1);                         \
        oA[dt] = MFMA16(av0, bpA0, oA[dt]);                                    \
        oA[dt] = MFMA16(av1, bpA1, oA[dt]);                                    \
        oB[dt] = MFMA16(av0, bpB0, oB[dt]);                                    \
        oB[dt] = MFMA16(av1, bpB1, oB[dt]);                                    \
      }                                                                        \
      __builtin_amdgcn_s_setprio(0);                                           \
    }                                                                          \
    if (!(LAST)) {                                                             \
      asm volatile("s_waitcnt vmcnt(0)" ::: "memory");                         \
      __builtin_amdgcn_s_barrier();                                            \
      MAc = MAn; MBc = MBn;                                                    \
    }                                                                          \
  }

  #pragma unroll 1
  for (int kc = 0; kc < 16; kc += 2) {
    ATT_BODY(K0, V0, K1, V1, mAc, mBc, mAn, mBn, kc, false)
    ATT_BODY(K1, V1, K0, V0, mAc, mBc, mAn, mBn, kc+1, (kc+1) == 15)
  }
#undef ATT_BODY

  lsumA += __shfl_xor(lsumA, 16, 64);
  lsumA += __shfl_xor(lsumA, 32, 64);
  lsumB += __shfl_xor(lsumB, 16, 64);
  lsumB += __shfl_xor(lsumB, 32, 64);
  const float linvA = 1.0f / lsumA;
  const float linvB = 1.0f / lsumB;

  #pragma unroll
  for (int dt = 0; dt < 4; dt++) {
    unsigned w0, w1, w2, w3;
    const float a0 = oA[dt][0]*linvA, a1 = oA[dt][1]*linvA;
    const float a2 = oA[dt][2]*linvA, a3 = oA[dt][3]*linvA;
    asm("v_cvt_pk_bf16_f32 %0, %1, %2" : "=v"(w0) : "v"(a0), "v"(a1));
    asm("v_cvt_pk_bf16_f32 %0, %1, %2" : "=v"(w1) : "v"(a2), "v"(a3));
    uint2 ow; ow.x = w0; ow.y = w1;
    *(uint2*)(PsAw + lr*72 + dt*16 + lg*4) = ow;
    const float c0 = oB[dt][0]*linvB, c1 = oB[dt][1]*linvB;
    const float c2 = oB[dt][2]*linvB, c3 = oB[dt][3]*linvB;
    asm("v_cvt_pk_bf16_f32 %0, %1, %2" : "=v"(w2) : "v"(c0), "v"(c1));
    asm("v_cvt_pk_bf16_f32 %0, %1, %2" : "=v"(w3) : "v"(c2), "v"(c3));
    uint2 ow2; ow2.x = w2; ow2.y = w3;
    *(uint2*)(PsBw + lr*72 + dt*16 + lg*4) = ow2;
  }
  #pragma unroll
  for (int rep = 0; rep < 2; rep++) {
    const int c = lane + rep*64;
    const int row = c >> 3, off = c & 7;
    const uint4 ovA = *(const uint4*)(PsAw + row*72 + off*8);
    *(uint4*)(attout + ((size_t)b*NN + qb*128 + w*32 + row)*DD + h*DHH + off*8) = ovA;
    const uint4 ovB = *(const uint4*)(PsBw + row*72 + off*8);
    *(uint4*)(attout + ((size_t)b*NN + qb*128 + w*32 + 16 + row)*DD + h*DHH + off*8) = ovB;
  }
}

// ---------------- exact score path (fp64) for what_to_prune ----------------
__global__ __launch_bounds__(512) void q0wv_kernel(const float* __restrict__ hlnf,
    const float* __restrict__ Wqkv, double* __restrict__ wv)
{
  const int bh = blockIdx.x, b = bh >> 3, h = bh & 7;
  __shared__ double red[512];
  __shared__ double q0s[64];
  {
    const int d = threadIdx.x & 63, cg = threadIdx.x >> 6;
    double acc = 0.0;
    #pragma unroll 8
    for (int c = cg*64; c < cg*64 + 64; c++)
      acc += (double)hlnf[(size_t)b*NN*DD + c] * (double)Wqkv[(size_t)c*1536 + h*64 + d];
    red[threadIdx.x] = acc;
    __syncthreads();
    if (threadIdx.x < 64) {
      double s = 0.0;
      #pragma unroll
      for (int g = 0; g < 8; g++) s += red[g*64 + d];
      q0s[d] = s;
    }
    __syncthreads();
  }
  const int c = threadIdx.x;
  const float4* wp = (const float4*)(Wqkv + (size_t)c*1536 + 512 + h*64);
  double acc = 0.0;
  #pragma unroll
  for (int dv = 0; dv < 16; dv++) {
    const float4 wq = wp[dv];
    acc += q0s[dv*4+0]*(double)wq.x + q0s[dv*4+1]*(double)wq.y
         + q0s[dv*4+2]*(double)wq.z + q0s[dv*4+3]*(double)wq.w;
  }
  wv[(size_t)bh*512 + c] = acc;
}

__global__ __launch_bounds__(256) void srow_kernel(const float* __restrict__ hlnf,
    const double* __restrict__ wv, const float* __restrict__ mask,
    double* __restrict__ srow)
{
  const int b = blockIdx.x, jc = blockIdx.y;
  const int jl = threadIdx.x >> 3;
  const int cg = threadIdx.x & 7;
  const int j  = jc*32 + jl;
  __shared__ double lw[8*512];
  __shared__ double red[32][8][9];
  for (int i = threadIdx.x; i < 4096; i += 256) lw[i] = wv[(size_t)b*4096 + i];
  __syncthreads();
  double acc[8] = {0,0,0,0,0,0,0,0};
  const float* xr = hlnf + ((size_t)b*NN + j)*DD;
  #pragma unroll
  for (int i = 0; i < 16; i++) {
    const int c = cg*4 + i*32;
    const float4 xv4 = *(const float4*)(xr + c);
    #pragma unroll
    for (int h = 0; h < 8; h++) {
      const double* lwc = lw + h*512 + c;
      acc[h] += (double)xv4.x*lwc[0] + (double)xv4.y*lwc[1]
              + (double)xv4.z*lwc[2] + (double)xv4.w*lwc[3];
    }
  }
  #pragma unroll
  for (int h = 0; h < 8; h++) red[jl][cg][h] = acc[h];
  __syncthreads();
  const int j2 = threadIdx.x >> 3, h2 = threadIdx.x & 7;
  double s = 0.0;
  #pragma unroll
  for (int g = 0; g < 8; g++) s += red[j2][g][h2];
  s *= 0.125;
  const float mval = mask[(size_t)b*NN*NN + jc*32 + j2];
  if (mval == 1.0f) s = -1e10;
  srow[((size_t)b*8 + h2)*NN + jc*32 + j2] = s;
}

// fused denominator + att (no max subtraction; fp64 exp safe, masked -> 0)
__global__ __launch_bounds__(1024) void sumatt_kernel(const double* __restrict__ srow,
    double* __restrict__ attv)
{
  const int b = blockIdx.x;
  const int t = threadIdx.x;
  __shared__ double e[8][1024];
  __shared__ double red[1024];
  __shared__ double sinv[8];
  const int h = t >> 7, j0 = t & 127;
  double ps = 0.0;
  #pragma unroll
  for (int i = 0; i < 8; i++) {
    const int j = j0 + i*128;
    const double v = exp(srow[((size_t)b*8 + h)*NN + j]);
    e[h][j] = v;
    ps += v;
  }
  red[t] = ps;
  __syncthreads();
  #pragma unroll
  for (int off = 64; off >= 1; off >>= 1) {
    if (j0 < off) red[t] += red[t + off];
    __syncthreads();
  }
  if (j0 == 0) sinv[h] = 1.0 / red[t];
  __syncthreads();
  double s = 0.0;
  #pragma unroll
  for (int hh = 0; hh < 8; hh++) s += e[hh][t] * sinv[hh];
  attv[b*NN + t] = (t == 0) ? -INFINITY : s * 0.125;
}

// rank-by-counting (exact stable-argsort semantics), parallelized
__global__ __launch_bounds__(256) void rank_kernel(const double* __restrict__ attv,
    float* __restrict__ dout, int offP, int offM, int offS)
{
  const int b = blockIdx.x, jc = blockIdx.y;
  const int t = threadIdx.x;
  __shared__ double a[1024];
  __shared__ int red[32][8];
  #pragma unroll
  for (int rep = 0; rep < 4; rep++)
    a[rep*256 + t] = attv[b*NN + rep*256 + t];
  __syncthreads();
  const int jl = t >> 3, kg = t & 7;
  const int j = jc*32 + jl;
  const double aj = a[j];
  int r = 0;
  #pragma unroll 8
  for (int i = 0; i < 128; i++) {
    const int idx = kg*128 + ((i + kg*2) & 127);
    const double ak = a[idx];
    r += ((ak > aj) || (ak == aj && idx < j)) ? 1 : 0;
  }
  red[jl][kg] = r;
  __syncthreads();
  if (t < 32) {
    int rr = 0;
    #pragma unroll
    for (int g = 0; g < 8; g++) rr += red[t][g];
    const int jj = jc*32 + t;
    if (rr >= 959 && rr <= 1022) dout[offP + b*64 + (rr - 959)] = (float)jj;
  }
  if (b == 0 && jc == 0) {
    if (t < 8)   dout[offM + t] = -1.0f;
    if (t < 128) dout[offS + t] = 0.0f;
  }
}

// ---------------------------------------------------------------------------
extern "C" void kernel_launch(void* const* d_in, const int* in_sizes, int n_in,
                              void* d_out, int out_size, void* d_ws, size_t ws_size,
                              hipStream_t stream) {
  (void)in_sizes; (void)n_in; (void)out_size; (void)ws_size;
  const float* x     = (const float*)d_in[0];
  const float* mask  = (const float*)d_in[1];
  const float* Wqkv  = (const float*)d_in[2];
  const float* Wout  = (const float*)d_in[3];
  const float* bout  = (const float*)d_in[4];
  const float* ln1g  = (const float*)d_in[5];
  const float* ln1b  = (const float*)d_in[6];
  const float* ln2g  = (const float*)d_in[7];
  const float* ln2b  = (const float*)d_in[8];
  const float* W1    = (const float*)d_in[9];
  const float* b1    = (const float*)d_in[10];
  const float* W2    = (const float*)d_in[11];
  const float* b2    = (const float*)d_in[12];
  float* dout = (float*)d_out;

  const size_t MB = 1ull << 20;
  char* ws = (char*)d_ws;
  short*  hln_bf = (short*)(ws + 0);           // 8 MB
  float*  hlnf   = (float*)(ws + 8*MB);        // 16 MB
  short*  Qg     = (short*)(ws + 24*MB);       // 8 MB
  short*  Kg     = (short*)(ws + 32*MB);       // 8 MB
  short*  Vtg    = (short*)(ws + 40*MB);       // 8 MB
  unsigned long long* mbits = (unsigned long long*)(ws + 48*MB); // 1 MB
  short*  Wqkvt  = (short*)(ws + 49*MB);       // 1.5 MB
  short*  Woutt  = (short*)(ws + 51*MB);       // 0.5 MB
  short*  W1t    = (short*)(ws + 52*MB);       // 2 MB
  short*  W2t    = (short*)(ws + 54*MB);       // 2 MB
  double* wvv    = (double*)(ws + 56*MB + 256*1024);   // 256 KB
  double* srow   = (double*)(ws + 57*MB);              // 512 KB
  double* attv   = (double*)(ws + 59*MB);              // 64 KB
  short*  attout = (short*)(ws + 60*MB);       // 8 MB
  short*  x1b    = (short*)(ws + 68*MB);       // 4 MB (bf16)
  short*  h2     = (short*)(ws + 84*MB);       // 8 MB
  short*  gbuf   = (short*)(ws + 0);           // 32 MB, reuses [0,32) (dead by MLP1)

  const int offP = BB*NN*DD;          // 4194304
  const int offM = offP + BB*64;      // 4194816
  const int offS = offM + BB;         // 4194824

  // 1) merged prep: LN1 + mask bitfield + all weight transposes
  prep_kernel<<<11776, 256, 0, stream>>>(x, ln1g, ln1b, hln_bf, hlnf,
      mask, mbits, Wqkv, Wout, W1, W2, Wqkvt, Woutt, W1t, W2t);

  // 2) exact fp64 score path -> what_to_prune (+ constant tails)
  q0wv_kernel<<<BB*HH, 512, 0, stream>>>(hlnf, Wqkv, wvv);
  srow_kernel<<<dim3(BB, 32), 256, 0, stream>>>(hlnf, wvv, mask, srow);
  sumatt_kernel<<<BB, 1024, 0, stream>>>(srow, attv);
  rank_kernel<<<dim3(BB, 32), 256, 0, stream>>>(attv, dout, offP, offM, offS);

  // 3) QKV projection (768 blocks = 3/CU uniform; depth-2)
  gemm_bt<128,0,3><<<dim3(64, 12), 256, 0, stream>>>(hln_bf, Wqkvt, BB*NN, 1536, 512,
      nullptr, nullptr, nullptr, nullptr, nullptr, Qg, Kg, Vtg);

  // 4) flash attention (XCD-swizzled grid; gl_lds K/V staging)
  attn_kernel<<<512, 256, 0, stream>>>(Qg, Kg, Vtg, mbits, attout);

  // 5) out-proj + bias + residual -> x1b (bf16); 512 blocks = 2/CU, depth-2
  gemm_bt<64,3,3><<<dim3(64, 8), 256, 0, stream>>>(attout, Woutt, BB*NN, 512, 512,
      bout, x, nullptr, nullptr, x1b, nullptr, nullptr, nullptr);

  // 6) LN2 (bf16 in -> bf16 out)
  ln2_kernel<<<BB*NN, 256, 0, stream>>>(x1b, ln2g, ln2b, h2);

  // 7) MLP1 + gelu -> gbuf; 2-buffer 2-phase (32KB -> 4/CU, one round)
  gemm_bt<128,2,2><<<dim3(64, 16), 256, 0, stream>>>(h2, W1t, BB*NN, 2048, 512,
      b1, nullptr, nullptr, nullptr, gbuf, nullptr, nullptr, nullptr);

  // 8) MLP2 + bias + bf16 residual -> final x (f32); depth-2
  gemm_bt<64,4,3><<<dim3(64, 8), 256, 0, stream>>>(gbuf, W2t, BB*NN, 512, 2048,
      b2, nullptr, x1b, dout, nullptr, nullptr, nullptr, nullptr);
}

// Round 13
// 176.349 us; speedup vs baseline: 1.1137x; 1.0724x over previous
//
#include <hip/hip_runtime.h>
#include <hip/hip_bf16.h>
#include <math.h>

// Problem constants
#define BB 8
#define NN 1024
#define DD 512
#define HH 8
#define DHH 64
#define MLPD 2048

typedef __attribute__((ext_vector_type(8))) short short8;
typedef __attribute__((ext_vector_type(4))) float f32x4;

#define MFMA16(a,b,c) __builtin_amdgcn_mfma_f32_16x16x32_bf16(a,b,c,0,0,0)

// 0.125 * log2(e): folded softmax scale (applied to Q at QKV epilogue)
#define QSCALE 0.18033688011112042f
// bit pattern of -1e9f
#define NEGBIG 0xCE6E6B28u

__device__ __forceinline__ short f2bf(float f) {
  union { float f; unsigned u; } x; x.f = f;
  unsigned r = x.u + 0x7FFFu + ((x.u >> 16) & 1u);
  return (short)(r >> 16);
}
__device__ __forceinline__ float bf2f(short s) {
  union { float f; unsigned u; } x;
  x.u = ((unsigned)(unsigned short)s) << 16;
  return x.f;
}

// async global->LDS, 16B per lane; LDS dest must be wave-uniform base
__device__ __forceinline__ void gl_lds16(const short* g, short* l) {
  __builtin_amdgcn_global_load_lds(
      (const __attribute__((address_space(1))) unsigned int*)g,
      (__attribute__((address_space(3))) unsigned int*)l, 16, 0, 0);
}

// fast gelu: tanh form, err <= ~1e-3 abs
__device__ __forceinline__ float gelu_fast(float t) {
  const float u = 0.7978845608028654f * (t + 0.044715f * t * t * t);
  const float e = __builtin_amdgcn_exp2f(u * 2.8853900817779268f); // e^{2u}
  return t - t * __builtin_amdgcn_rcpf(e + 1.0f);                  // t*e/(e+1)
}

// wave-wide fp64 sum (all lanes get result)
__device__ __forceinline__ double wsum64(double v) {
  #pragma unroll
  for (int o = 32; o >= 1; o >>= 1) v += __shfl_xor(v, o, 64);
  return v;
}

// ------- merged prep (latency-optimized):
//   blocks 0..2047     LN1, wave-per-row (4 rows/block)
//   blocks 2048..4095  maskpack via ballot, wave-per-row
//   blocks 4096..7167  weight transpose x4
__global__ __launch_bounds__(256) void prep_kernel(
    const float* __restrict__ x, const float* __restrict__ ln1g,
    const float* __restrict__ ln1b, short* __restrict__ hln_bf,
    float* __restrict__ hlnf,
    const float* __restrict__ mask, unsigned long long* __restrict__ mbits,
    const float* __restrict__ Wqkv, const float* __restrict__ Wout,
    const float* __restrict__ W1,   const float* __restrict__ W2,
    short* __restrict__ Wqkvt, short* __restrict__ Woutt,
    short* __restrict__ W1t,   short* __restrict__ W2t)
{
  const int id = blockIdx.x;
  const int tid = threadIdx.x;
  const int w = tid >> 6, lane = tid & 63;
  if (id < 2048) {
    // ---- LN1: wave per row; lane holds 8 consecutive floats ----
    const int row = id*4 + w;
    const float* xr = x + (size_t)row*DD + lane*8;
    const float4 a = *(const float4*)xr;
    const float4 bv = *(const float4*)(xr + 4);
    double s = ((double)a.x + (double)a.y) + ((double)a.z + (double)a.w)
             + ((double)bv.x + (double)bv.y) + ((double)bv.z + (double)bv.w);
    const double mu = wsum64(s) * (1.0/512.0);
    const double d0 = (double)a.x - mu,  d1 = (double)a.y - mu;
    const double d2 = (double)a.z - mu,  d3 = (double)a.w - mu;
    const double d4 = (double)bv.x - mu, d5 = (double)bv.y - mu;
    const double d6 = (double)bv.z - mu, d7 = (double)bv.w - mu;
    double q = (d0*d0 + d1*d1) + (d2*d2 + d3*d3)
             + (d4*d4 + d5*d5) + (d6*d6 + d7*d7);
    const double var = wsum64(q) * (1.0/512.0);
    const float rs = (float)(1.0 / sqrt(var + 1e-5));
    const float mf = (float)mu;
    const float4 g0 = *(const float4*)(ln1g + lane*8);
    const float4 g1 = *(const float4*)(ln1g + lane*8 + 4);
    const float4 b0 = *(const float4*)(ln1b + lane*8);
    const float4 b1v = *(const float4*)(ln1b + lane*8 + 4);
    float y[8];
    y[0] = (a.x - mf)*rs*g0.x + b0.x;  y[1] = (a.y - mf)*rs*g0.y + b0.y;
    y[2] = (a.z - mf)*rs*g0.z + b0.z;  y[3] = (a.w - mf)*rs*g0.w + b0.w;
    y[4] = (bv.x - mf)*rs*g1.x + b1v.x; y[5] = (bv.y - mf)*rs*g1.y + b1v.y;
    y[6] = (bv.z - mf)*rs*g1.z + b1v.z; y[7] = (bv.w - mf)*rs*g1.w + b1v.w;
    float* of = hlnf + (size_t)row*DD + lane*8;
    *(float4*)of       = (float4){y[0], y[1], y[2], y[3]};
    *(float4*)(of + 4) = (float4){y[4], y[5], y[6], y[7]};
    short8 ob;
    #pragma unroll
    for (int i = 0; i < 8; i++) ob[i] = f2bf(y[i]);
    *(short8*)(hln_bf + (size_t)row*DD + lane*8) = ob;
  } else if (id < 4096) {
    // ---- maskpack via ballot: wave per mask row (1024 floats -> 16 words)
    const int row = (id - 2048)*4 + w;
    const float* p = mask + (size_t)row*NN;
    unsigned long long myword = 0;
    #pragma unroll
    for (int i = 0; i < 16; i++) {
      const float v = p[i*64 + lane];           // coalesced 256B per load
      const unsigned long long m = __ballot(v == 1.0f);
      if (lane == i) myword = m;
    }
    if (lane < 16) mbits[(size_t)row*16 + lane] = myword;
  } else {
    // ---- weight transpose + f32->bf16 ----
    const int id2 = id - 4096;
    const float* W; short* Wt; int K, N, t;
    if (id2 < 768)       { W = Wqkv; Wt = Wqkvt; K = 512;  N = 1536; t = id2; }
    else if (id2 < 1024) { W = Wout; Wt = Woutt; K = 512;  N = 512;  t = id2 - 768; }
    else if (id2 < 2048) { W = W1;   Wt = W1t;   K = 512;  N = 2048; t = id2 - 1024; }
    else                 { W = W2;   Wt = W2t;   K = 2048; N = 512;  t = id2 - 2048; }
    const int nx = N >> 5;
    const int n0 = (t % nx)*32, k0 = (t / nx)*32;
    __shared__ float tile[32][33];
    const int tx = tid & 31, ty = tid >> 5;
    #pragma unroll
    for (int j = 0; j < 4; j++)
      tile[ty + j*8][tx] = W[(size_t)(k0 + ty + j*8)*N + n0 + tx];
    __syncthreads();
    #pragma unroll
    for (int j = 0; j < 4; j++)
      Wt[(size_t)(n0 + ty + j*8)*K + k0 + tx] = f2bf(tile[tx][ty + j*8]);
  }
}

// ---------------- LN2: bf16 in -> bf16 out, wave-per-row -------------------
__global__ __launch_bounds__(256) void ln2_kernel(const short* __restrict__ xb,
    const float* __restrict__ gam, const float* __restrict__ bet,
    short* __restrict__ ob)
{
  const int w = threadIdx.x >> 6, lane = threadIdx.x & 63;
  const int row = blockIdx.x*4 + w;
  const short8 xs = *(const short8*)(xb + (size_t)row*DD + lane*8);
  float v[8];
  #pragma unroll
  for (int i = 0; i < 8; i++) v[i] = bf2f(xs[i]);
  double s = ((double)v[0] + (double)v[1]) + ((double)v[2] + (double)v[3])
           + ((double)v[4] + (double)v[5]) + ((double)v[6] + (double)v[7]);
  const double mu = wsum64(s) * (1.0/512.0);
  double q = 0.0;
  #pragma unroll
  for (int i = 0; i < 8; i++) { const double d = (double)v[i] - mu; q += d*d; }
  const double var = wsum64(q) * (1.0/512.0);
  const float rs = (float)(1.0 / sqrt(var + 1e-5));
  const float mf = (float)mu;
  const float4 g0 = *(const float4*)(gam + lane*8);
  const float4 g1 = *(const float4*)(gam + lane*8 + 4);
  const float4 b0 = *(const float4*)(bet + lane*8);
  const float4 b1v = *(const float4*)(bet + lane*8 + 4);
  const float gg[8] = {g0.x,g0.y,g0.z,g0.w,g1.x,g1.y,g1.z,g1.w};
  const float bb[8] = {b0.x,b0.y,b0.z,b0.w,b1v.x,b1v.y,b1v.z,b1v.w};
  short8 o;
  #pragma unroll
  for (int i = 0; i < 8; i++) o[i] = f2bf((v[i] - mf)*rs*gg[i] + bb[i]);
  *(short8*)(ob + (size_t)row*DD + lane*8) = o;
}

// ---------------- GEMM: A[M][K](bf16) x Bt[N][K](bf16) -> epilogues --------
// 128xBN tile, BK=32, 4 waves (2x2). NBUF=3: depth-2, counted vmcnt.
// NBUF=2: 2-phase, 32KB LDS -> 4+ blocks/CU.
// EPI 0: QKV scatter -> Qg(scaled)/Kg[bh][n][d], Vtg[bh][d][n]   (bf16)
// EPI 2: + bias[col], fast gelu -> bf16 out
// EPI 3: + bias[col] + res_f32[row][col] -> bf16 out   (outproj -> x1b)
// EPI 4: + bias[col] + res_bf16[row][col] -> f32 out   (MLP2 -> dout)
template<int BN, int EPI, int NBUF>
__global__ __launch_bounds__(256) void gemm_bt(
    const short* __restrict__ A, const short* __restrict__ Bt,
    int M, int N, int K,
    const float* __restrict__ bias, const float* __restrict__ res,
    const short* __restrict__ resb,
    float* __restrict__ outf, short* __restrict__ outb,
    short* __restrict__ outQ, short* __restrict__ outK, short* __restrict__ outVt)
{
  constexpr int CH = 8 + BN/16;          // 1KB chunks per K-tile (A:8, B:BN/16)
  constexpr int L  = CH/4;               // gl_lds per wave per tile (4 or 3)
  constexpr int BUFS = (128 + BN)*32;    // shorts per buffer
  __shared__ __align__(16) short lds[NBUF*BUFS];
  const int tid = threadIdx.x;
  const int bm0 = blockIdx.x * 128;
  const int bn0 = blockIdx.y * BN;
  const int lane = tid & 63, wid = tid >> 6;
  const int wm = (wid >> 1) * 64, wn = (wid & 1) * (BN/2);
  const int lr = lane & 15, lg = lane >> 4;
  constexpr int NT = BN/32;              // n-tiles of 16 per wave (4 or 2)

  const short* gsrc[L];
  int loff[L];
  const int scc = (((lane & 3) ^ ((lane >> 3) & 3)))*8;   // pre-swizzled col
  #pragma unroll
  for (int i = 0; i < L; i++) {
    const int c = i*4 + wid;
    const int rr = ((c < 8) ? c : c - 8)*16 + (lane >> 2);
    gsrc[i] = (c < 8) ? (A + (size_t)(bm0 + rr)*K + scc)
                      : (Bt + (size_t)(bn0 + rr)*K + scc);
    loff[i] = c*512;
  }
  const int xs = (lr >> 1) & 3;          // fragment-read slot XOR

  f32x4 acc[4][NT];
  #pragma unroll
  for (int i = 0; i < 4; i++)
    #pragma unroll
    for (int j = 0; j < NT; j++) acc[i][j] = f32x4{0.f,0.f,0.f,0.f};

  const int nsteps = K >> 5;

  auto STAGE = [&](int buf, int t) {
    short* dst = lds + buf*BUFS;
    const int ko = t*32;
    #pragma unroll
    for (int i = 0; i < L; i++)
      gl_lds16(gsrc[i] + ko, dst + loff[i]);
  };
  auto COMPUTE = [&](const short* bufA) {
    const short* bufB = bufA + 4096;
    short8 af[4], bfr[NT];
    #pragma unroll
    for (int mt = 0; mt < 4; mt++)
      af[mt] = *(const short8*)(bufA + (wm + mt*16 + lr)*32 + (lg ^ xs)*8);
    #pragma unroll
    for (int nt = 0; nt < NT; nt++)
      bfr[nt] = *(const short8*)(bufB + (wn + nt*16 + lr)*32 + (lg ^ xs)*8);
    __builtin_amdgcn_s_setprio(1);
    #pragma unroll
    for (int mt = 0; mt < 4; mt++)
      #pragma unroll
      for (int nt = 0; nt < NT; nt++)
        acc[mt][nt] = MFMA16(af[mt], bfr[nt], acc[mt][nt]);
    __builtin_amdgcn_s_setprio(0);
  };

  if constexpr (NBUF == 2) {
    STAGE(0, 0);
    asm volatile("s_waitcnt vmcnt(0)" ::: "memory");
    __builtin_amdgcn_s_barrier();
    int cur = 0;
    #pragma unroll 1
    for (int t = 0; t < nsteps; t++) {
      if (t + 1 < nsteps) STAGE(cur ^ 1, t + 1);
      COMPUTE(lds + cur*BUFS);
      asm volatile("s_waitcnt vmcnt(0)" ::: "memory");
      __builtin_amdgcn_s_barrier();
      cur ^= 1;
    }
  } else {
    STAGE(0, 0);
    STAGE(1, 1);
    int cur = 0;
    #pragma unroll 1
    for (int t = 0; t < nsteps; t++) {
      if (t == nsteps - 1) {
        asm volatile("s_waitcnt vmcnt(0)" ::: "memory");
      } else if constexpr (L == 4) {
        asm volatile("s_waitcnt vmcnt(4)" ::: "memory");
      } else {
        asm volatile("s_waitcnt vmcnt(3)" ::: "memory");
      }
      __builtin_amdgcn_s_barrier();
      if (t + 2 < nsteps) {
        const int bnext = (cur == 0) ? 2 : cur - 1;   // (cur+2)%3
        STAGE(bnext, t + 2);
      }
      COMPUTE(lds + cur*BUFS);
      cur = (cur == 2) ? 0 : cur + 1;
    }
  }

  if (EPI == 0 && bn0 >= 1024) {
    #pragma unroll
    for (int mt = 0; mt < 4; mt++)
      #pragma unroll
      for (int nt = 0; nt < NT; nt++) {
        const int row0 = bm0 + wm + mt*16 + lg*4;
        const int b = row0 >> 10, tok0 = row0 & 1023;
        const int c2 = bn0 + wn + nt*16 + lr - 1024;
        const int h = c2 >> 6, d = c2 & 63;
        unsigned lo2, hi2;
        asm("v_cvt_pk_bf16_f32 %0, %1, %2" : "=v"(lo2)
            : "v"(acc[mt][nt][0]), "v"(acc[mt][nt][1]));
        asm("v_cvt_pk_bf16_f32 %0, %1, %2" : "=v"(hi2)
            : "v"(acc[mt][nt][2]), "v"(acc[mt][nt][3]));
        uint2 pw; pw.x = lo2; pw.y = hi2;
        *(uint2*)(outVt + (((size_t)(b*HH + h))*DHH + d)*NN + tok0) = pw;
      }
    return;
  }

  #pragma unroll
  for (int mt = 0; mt < 4; mt++)
    #pragma unroll
    for (int nt = 0; nt < NT; nt++)
      #pragma unroll
      for (int r = 0; r < 4; r++) {
        const int row = bm0 + wm + mt*16 + lg*4 + r;
        const int col = bn0 + wn + nt*16 + lr;
        const float v = acc[mt][nt][r];
        if (EPI == 0) {
          const int b = row >> 10, tok = row & 1023;
          if (col < 512) {
            const int h = col >> 6, d = col & 63;
            outQ[(((size_t)(b*HH + h))*NN + tok)*DHH + d] = f2bf(v * QSCALE);
          } else {
            const int c2 = col - 512, h = c2 >> 6, d = c2 & 63;
            outK[(((size_t)(b*HH + h))*NN + tok)*DHH + d] = f2bf(v);
          }
        } else if (EPI == 2) {
          outb[(size_t)row*N + col] = f2bf(gelu_fast(v + bias[col]));
        } else if (EPI == 3) {
          outb[(size_t)row*N + col] = f2bf(v + bias[col] + res[(size_t)row*N + col]);
        } else {  // EPI 4
          outf[(size_t)row*N + col] = v + bias[col] + bf2f(resb[(size_t)row*N + col]);
        }
      }
}

// ---------------- flash attention (no-max), swapped QK^T, bit-mask --------
__global__ __launch_bounds__(256) void attn_kernel(
    const short* __restrict__ Qg, const short* __restrict__ Kg,
    const short* __restrict__ Vtg, const unsigned long long* __restrict__ mb,
    short* __restrict__ attout)
{
  const int id = blockIdx.x;
  const int bh = (id & 7)*8 + ((id >> 3) & 7);   // same-bh blocks -> same XCD
  const int qb = id >> 6;                        // 0..7
  const int b = bh >> 3, h = bh & 7;
  const int tid = threadIdx.x, lane = tid & 63, w = tid >> 6;
  const int lr = lane & 15, lg = lane >> 4;

  __shared__ __align__(16) short K0[64*64], K1[64*64];
  __shared__ __align__(16) short V0[64*64], V1[64*64];
  __shared__ __align__(16) short PsA[4][16*72], PsB[4][16*72];

  const int qA = qb*128 + w*32 + lr;
  const int qB = qA + 16;
  short* PsAw = &PsA[w][0];
  short* PsBw = &PsB[w][0];

  const size_t qbase = (size_t)bh*NN*DHH;
  const short8 bqA0 = *(const short8*)(Qg + qbase + (size_t)qA*DHH + lg*8);
  const short8 bqA1 = *(const short8*)(Qg + qbase + (size_t)qA*DHH + 32 + lg*8);
  const short8 bqB0 = *(const short8*)(Qg + qbase + (size_t)qB*DHH + lg*8);
  const short8 bqB1 = *(const short8*)(Qg + qbase + (size_t)qB*DHH + 32 + lg*8);

  const unsigned long long* mrowA = mb + ((size_t)b*NN + qA)*16;
  const unsigned long long* mrowB = mb + ((size_t)b*NN + qB)*16;

  const int l8 = lane >> 3;
  const int uu = (lane & 7) ^ l8;
  const short* kgA = Kg + ((size_t)bh*NN + w*16 + l8)*64 + uu*8;
  const short* kgB = kgA + 8*64;
  const short* vgA = Vtg + ((size_t)bh*DHH + w*16 + l8)*NN + uu*8;
  const short* vgB = vgA + 8*NN;
  auto STAGE = [&](short* kb, short* vb, int kc) {
    gl_lds16(kgA + kc*4096, kb + (w*16)*64);
    gl_lds16(kgB + kc*4096, kb + (w*16 + 8)*64);
    gl_lds16(vgA + kc*64,   vb + (w*16)*64);
    gl_lds16(vgB + kc*64,   vb + (w*16 + 8)*64);
  };
  const int xo0 = ((lg ^ (lr & 7)))*8;
  const int xo1 = (((lg ^ (lr & 7))) ^ 4)*8;

  unsigned long long mAc, mBc, mAn, mBn;

  STAGE(K0, V0, 0);
  mAc = mrowA[0]; mBc = mrowB[0];
  asm volatile("s_waitcnt vmcnt(0)" ::: "memory");
  __builtin_amdgcn_s_barrier();

  f32x4 oA[4], oB[4];
  #pragma unroll
  for (int dt = 0; dt < 4; dt++) { oA[dt] = f32x4{0.f,0.f,0.f,0.f}; oB[dt] = f32x4{0.f,0.f,0.f,0.f}; }
  float lsumA = 0.f, lsumB = 0.f;

#define ATT_BODY(CK, CV, NK, NV, MAc, MBc, MAn, MBn, KC, LAST)                 \
  {                                                                            \
    if (!(LAST)) {                                                             \
      STAGE(NK, NV, (KC)+1);                                                   \
      MAn = mrowA[(KC)+1]; MBn = mrowB[(KC)+1];                                \
    }                                                                          \
    f32x4 sA[4], sB[4];                                                        \
    {                                                                          \
      const unsigned long long mqA = MAc >> (lg*4);                            \
      const unsigned loA = (unsigned)mqA, hiA = (unsigned)(mqA >> 32);         \
      const unsigned long long mqB = MBc >> (lg*4);                            \
      const unsigned loB = (unsigned)mqB, hiB = (unsigned)(mqB >> 32);         \
      _Pragma("unroll")                                                        \
      for (int nt = 0; nt < 4; nt++) {                                         \
        const unsigned wA = (nt < 2) ? loA : hiA;                              \
        const unsigned wB = (nt < 2) ? loB : hiB;                              \
        const int sh = (nt & 1) * 16;                                          \
        _Pragma("unroll")                                                      \
        for (int rr = 0; rr < 4; rr++) {                                       \
          const unsigned bA = (wA >> (sh + rr)) & 1u;                          \
          const unsigned bB = (wB >> (sh + rr)) & 1u;                          \
          sA[nt][rr] = __uint_as_float((0u - bA) & NEGBIG);                    \
          sB[nt][rr] = __uint_as_float((0u - bB) & NEGBIG);                    \
        }                                                                      \
      }                                                                        \
    }                                                                          \
    __builtin_amdgcn_s_setprio(1);                                             \
    _Pragma("unroll")                                                          \
    for (int nt = 0; nt < 4; nt++) {                                           \
      const short* kr = (CK) + (nt*16 + lr)*64;                                \
      const short8 ak0 = *(const short8*)(kr + xo0);                           \
      const short8 ak1 = *(const short8*)(kr + xo1);                           \
      sA[nt] = MFMA16(ak0, bqA0, sA[nt]);                                      \
      sA[nt] = MFMA16(ak1, bqA1, sA[nt]);                                      \
      sB[nt] = MFMA16(ak0, bqB0, sB[nt]);                                      \
      sB[nt] = MFMA16(ak1, bqB1, sB[nt]);                                      \
    }                                                                          \
    __builtin_amdgcn_s_setprio(0);                                             \
    _Pragma("unroll")                                                          \
    for (int nt = 0; nt < 4; nt++) {                                           \
      const float a0 = __builtin_amdgcn_exp2f(sA[nt][0]);                      \
      const float a1 = __builtin_amdgcn_exp2f(sA[nt][1]);                      \
      const float a2 = __builtin_amdgcn_exp2f(sA[nt][2]);                      \
      const float a3 = __builtin_amdgcn_exp2f(sA[nt][3]);                      \
      lsumA += (a0 + a1) + (a2 + a3);                                          \
      unsigned plo, phi;                                                       \
      asm("v_cvt_pk_bf16_f32 %0, %1, %2" : "=v"(plo) : "v"(a0), "v"(a1));      \
      asm("v_cvt_pk_bf16_f32 %0, %1, %2" : "=v"(phi) : "v"(a2), "v"(a3));      \
      uint2 pw; pw.x = plo; pw.y = phi;                                        \
      *(uint2*)(PsAw + lr*72 + nt*16 + lg*4) = pw;                             \
      const float c0 = __builtin_amdgcn_exp2f(sB[nt][0]);                      \
      const float c1 = __builtin_amdgcn_exp2f(sB[nt][1]);                      \
      const float c2 = __builtin_amdgcn_exp2f(sB[nt][2]);                      \
      const float c3 = __builtin_amdgcn_exp2f(sB[nt][3]);                      \
      lsumB += (c0 + c1) + (c2 + c3);                                          \
      unsigned qlo, qhi;                                                       \
      asm("v_cvt_pk_bf16_f32 %0, %1, %2" : "=v"(qlo) : "v"(c0), "v"(c1));      \
      asm("v_cvt_pk_bf16_f32 %0, %1, %2" : "=v"(qhi) : "v"(c2), "v"(c3));      \
      uint2 qw; qw.x = qlo; qw.y = qhi;                                        \
      *(uint2*)(PsBw + lr*72 + nt*16 + lg*4) = qw;                             \
    }                                                                          \
    {                                                                          \
      const short8 bpA0 = *(const short8*)(PsAw + lr*72 + lg*8);               \
      const short8 bpA1 = *(const short8*)(PsAw + lr*72 + 32 + lg*8);          \
      const short8 bpB0 = *(const short8*)(PsBw + lr*72 + lg*8);               \
      const short8 bpB1 = *(const short8*)(PsBw + lr*72 + 32 + lg*8);          \
      __builtin_amdgcn_s_setprio(1);                                           \
      _Pragma("unroll")                                                        \
      for (int dt = 0; dt < 4; dt++) {                                         \
        const short* vr = (CV) + (dt*16 + lr)*64;                              \
        const short8 av0 = *(const short8*)(vr + xo0);                         \
        const short8 av1 = *(const short8*)(vr + xo1);                         \
        oA[dt] = MFMA16(av0, bpA0, oA[dt]);                                    \
        oA[dt] = MFMA16(av1, bpA1, oA[dt]);                                    \
        oB[dt] = MFMA16(av0, bpB0, oB[dt]);                                    \
        oB[dt] = MFMA16(av1, bpB1, oB[dt]);                                    \
      }                                                                        \
      __builtin_amdgcn_s_setprio(0);                                           \
    }                                                                          \
    if (!(LAST)) {                                                             \
      asm volatile("s_waitcnt vmcnt(0)" ::: "memory");                         \
      __builtin_amdgcn_s_barrier();                                            \
      MAc = MAn; MBc = MBn;                                                    \
    }                                                                          \
  }

  #pragma unroll 1
  for (int kc = 0; kc < 16; kc += 2) {
    ATT_BODY(K0, V0, K1, V1, mAc, mBc, mAn, mBn, kc, false)
    ATT_BODY(K1, V1, K0, V0, mAc, mBc, mAn, mBn, kc+1, (kc+1) == 15)
  }
#undef ATT_BODY

  lsumA += __shfl_xor(lsumA, 16, 64);
  lsumA += __shfl_xor(lsumA, 32, 64);
  lsumB += __shfl_xor(lsumB, 16, 64);
  lsumB += __shfl_xor(lsumB, 32, 64);
  const float linvA = 1.0f / lsumA;
  const float linvB = 1.0f / lsumB;

  #pragma unroll
  for (int dt = 0; dt < 4; dt++) {
    unsigned w0, w1, w2, w3;
    const float a0 = oA[dt][0]*linvA, a1 = oA[dt][1]*linvA;
    const float a2 = oA[dt][2]*linvA, a3 = oA[dt][3]*linvA;
    asm("v_cvt_pk_bf16_f32 %0, %1, %2" : "=v"(w0) : "v"(a0), "v"(a1));
    asm("v_cvt_pk_bf16_f32 %0, %1, %2" : "=v"(w1) : "v"(a2), "v"(a3));
    uint2 ow; ow.x = w0; ow.y = w1;
    *(uint2*)(PsAw + lr*72 + dt*16 + lg*4) = ow;
    const float c0 = oB[dt][0]*linvB, c1 = oB[dt][1]*linvB;
    const float c2 = oB[dt][2]*linvB, c3 = oB[dt][3]*linvB;
    asm("v_cvt_pk_bf16_f32 %0, %1, %2" : "=v"(w2) : "v"(c0), "v"(c1));
    asm("v_cvt_pk_bf16_f32 %0, %1, %2" : "=v"(w3) : "v"(c2), "v"(c3));
    uint2 ow2; ow2.x = w2; ow2.y = w3;
    *(uint2*)(PsBw + lr*72 + dt*16 + lg*4) = ow2;
  }
  #pragma unroll
  for (int rep = 0; rep < 2; rep++) {
    const int c = lane + rep*64;
    const int row = c >> 3, off = c & 7;
    const uint4 ovA = *(const uint4*)(PsAw + row*72 + off*8);
    *(uint4*)(attout + ((size_t)b*NN + qb*128 + w*32 + row)*DD + h*DHH + off*8) = ovA;
    const uint4 ovB = *(const uint4*)(PsBw + row*72 + off*8);
    *(uint4*)(attout + ((size_t)b*NN + qb*128 + w*32 + 16 + row)*DD + h*DHH + off*8) = ovB;
  }
}

// ---------------- exact score path (fp64) for what_to_prune ----------------
__global__ __launch_bounds__(512) void q0wv_kernel(const float* __restrict__ hlnf,
    const float* __restrict__ Wqkv, double* __restrict__ wv)
{
  const int bh = blockIdx.x, b = bh >> 3, h = bh & 7;
  __shared__ double red[512];
  __shared__ double q0s[64];
  {
    const int d = threadIdx.x & 63, cg = threadIdx.x >> 6;
    double acc = 0.0;
    #pragma unroll 8
    for (int c = cg*64; c < cg*64 + 64; c++)
      acc += (double)hlnf[(size_t)b*NN*DD + c] * (double)Wqkv[(size_t)c*1536 + h*64 + d];
    red[threadIdx.x] = acc;
    __syncthreads();
    if (threadIdx.x < 64) {
      double s = 0.0;
      #pragma unroll
      for (int g = 0; g < 8; g++) s += red[g*64 + d];
      q0s[d] = s;
    }
    __syncthreads();
  }
  const int c = threadIdx.x;
  const float4* wp = (const float4*)(Wqkv + (size_t)c*1536 + 512 + h*64);
  double acc = 0.0;
  #pragma unroll
  for (int dv = 0; dv < 16; dv++) {
    const float4 wq = wp[dv];
    acc += q0s[dv*4+0]*(double)wq.x + q0s[dv*4+1]*(double)wq.y
         + q0s[dv*4+2]*(double)wq.z + q0s[dv*4+3]*(double)wq.w;
  }
  wv[(size_t)bh*512 + c] = acc;
}

__global__ __launch_bounds__(256) void srow_kernel(const float* __restrict__ hlnf,
    const double* __restrict__ wv, const float* __restrict__ mask,
    double* __restrict__ srow)
{
  const int b = blockIdx.x, jc = blockIdx.y;
  const int jl = threadIdx.x >> 3;
  const int cg = threadIdx.x & 7;
  const int j  = jc*32 + jl;
  __shared__ double lw[8*512];
  __shared__ double red[32][8][9];
  for (int i = threadIdx.x; i < 4096; i += 256) lw[i] = wv[(size_t)b*4096 + i];
  __syncthreads();
  double acc[8] = {0,0,0,0,0,0,0,0};
  const float* xr = hlnf + ((size_t)b*NN + j)*DD;
  #pragma unroll
  for (int i = 0; i < 16; i++) {
    const int c = cg*4 + i*32;
    const float4 xv4 = *(const float4*)(xr + c);
    #pragma unroll
    for (int h = 0; h < 8; h++) {
      const double* lwc = lw + h*512 + c;
      acc[h] += (double)xv4.x*lwc[0] + (double)xv4.y*lwc[1]
              + (double)xv4.z*lwc[2] + (double)xv4.w*lwc[3];
    }
  }
  #pragma unroll
  for (int h = 0; h < 8; h++) red[jl][cg][h] = acc[h];
  __syncthreads();
  const int j2 = threadIdx.x >> 3, h2 = threadIdx.x & 7;
  double s = 0.0;
  #pragma unroll
  for (int g = 0; g < 8; g++) s += red[j2][g][h2];
  s *= 0.125;
  const float mval = mask[(size_t)b*NN*NN + jc*32 + j2];
  if (mval == 1.0f) s = -1e10;
  srow[((size_t)b*8 + h2)*NN + jc*32 + j2] = s;
}

// fused denominator + att (no max subtraction; fp64 exp safe, masked -> 0)
__global__ __launch_bounds__(1024) void sumatt_kernel(const double* __restrict__ srow,
    double* __restrict__ attv)
{
  const int b = blockIdx.x;
  const int t = threadIdx.x;
  __shared__ double e[8][1024];
  __shared__ double red[1024];
  __shared__ double sinv[8];
  const int h = t >> 7, j0 = t & 127;
  double ps = 0.0;
  #pragma unroll
  for (int i = 0; i < 8; i++) {
    const int j = j0 + i*128;
    const double v = exp(srow[((size_t)b*8 + h)*NN + j]);
    e[h][j] = v;
    ps += v;
  }
  red[t] = ps;
  __syncthreads();
  #pragma unroll
  for (int off = 64; off >= 1; off >>= 1) {
    if (j0 < off) red[t] += red[t + off];
    __syncthreads();
  }
  if (j0 == 0) sinv[h] = 1.0 / red[t];
  __syncthreads();
  double s = 0.0;
  #pragma unroll
  for (int hh = 0; hh < 8; hh++) s += e[hh][t] * sinv[hh];
  attv[b*NN + t] = (t == 0) ? -INFINITY : s * 0.125;
}

// rank-by-counting (exact stable-argsort semantics), parallelized
__global__ __launch_bounds__(256) void rank_kernel(const double* __restrict__ attv,
    float* __restrict__ dout, int offP, int offM, int offS)
{
  const int b = blockIdx.x, jc = blockIdx.y;
  const int t = threadIdx.x;
  __shared__ double a[1024];
  __shared__ int red[32][8];
  #pragma unroll
  for (int rep = 0; rep < 4; rep++)
    a[rep*256 + t] = attv[b*NN + rep*256 + t];
  __syncthreads();
  const int jl = t >> 3, kg = t & 7;
  const int j = jc*32 + jl;
  const double aj = a[j];
  int r = 0;
  #pragma unroll 8
  for (int i = 0; i < 128; i++) {
    const int idx = kg*128 + ((i + kg*2) & 127);
    const double ak = a[idx];
    r += ((ak > aj) || (ak == aj && idx < j)) ? 1 : 0;
  }
  red[jl][kg] = r;
  __syncthreads();
  if (t < 32) {
    int rr = 0;
    #pragma unroll
    for (int g = 0; g < 8; g++) rr += red[t][g];
    const int jj = jc*32 + t;
    if (rr >= 959 && rr <= 1022) dout[offP + b*64 + (rr - 959)] = (float)jj;
  }
  if (b == 0 && jc == 0) {
    if (t < 8)   dout[offM + t] = -1.0f;
    if (t < 128) dout[offS + t] = 0.0f;
  }
}

// ---------------------------------------------------------------------------
extern "C" void kernel_launch(void* const* d_in, const int* in_sizes, int n_in,
                              void* d_out, int out_size, void* d_ws, size_t ws_size,
                              hipStream_t stream) {
  (void)in_sizes; (void)n_in; (void)out_size; (void)ws_size;
  const float* x     = (const float*)d_in[0];
  const float* mask  = (const float*)d_in[1];
  const float* Wqkv  = (const float*)d_in[2];
  const float* Wout  = (const float*)d_in[3];
  const float* bout  = (const float*)d_in[4];
  const float* ln1g  = (const float*)d_in[5];
  const float* ln1b  = (const float*)d_in[6];
  const float* ln2g  = (const float*)d_in[7];
  const float* ln2b  = (const float*)d_in[8];
  const float* W1    = (const float*)d_in[9];
  const float* b1    = (const float*)d_in[10];
  const float* W2    = (const float*)d_in[11];
  const float* b2    = (const float*)d_in[12];
  float* dout = (float*)d_out;

  const size_t MB = 1ull << 20;
  char* ws = (char*)d_ws;
  short*  hln_bf = (short*)(ws + 0);           // 8 MB
  float*  hlnf   = (float*)(ws + 8*MB);        // 16 MB
  short*  Qg     = (short*)(ws + 24*MB);       // 8 MB
  short*  Kg     = (short*)(ws + 32*MB);       // 8 MB
  short*  Vtg    = (short*)(ws + 40*MB);       // 8 MB
  unsigned long long* mbits = (unsigned long long*)(ws + 48*MB); // 1 MB
  short*  Wqkvt  = (short*)(ws + 49*MB);       // 1.5 MB
  short*  Woutt  = (short*)(ws + 51*MB);       // 0.5 MB
  short*  W1t    = (short*)(ws + 52*MB);       // 2 MB
  short*  W2t    = (short*)(ws + 54*MB);       // 2 MB
  double* wvv    = (double*)(ws + 56*MB + 256*1024);   // 256 KB
  double* srow   = (double*)(ws + 57*MB);              // 512 KB
  double* attv   = (double*)(ws + 59*MB);              // 64 KB
  short*  attout = (short*)(ws + 60*MB);       // 8 MB
  short*  x1b    = (short*)(ws + 68*MB);       // 4 MB (bf16)
  short*  h2     = (short*)(ws + 84*MB);       // 8 MB
  short*  gbuf   = (short*)(ws + 0);           // 32 MB, reuses [0,32) (dead by MLP1)

  const int offP = BB*NN*DD;          // 4194304
  const int offM = offP + BB*64;      // 4194816
  const int offS = offM + BB;         // 4194824

  // 1) merged prep: LN1 (wave/row) + maskpack (ballot) + weight transposes
  prep_kernel<<<7168, 256, 0, stream>>>(x, ln1g, ln1b, hln_bf, hlnf,
      mask, mbits, Wqkv, Wout, W1, W2, Wqkvt, Woutt, W1t, W2t);

  // 2) exact fp64 score path -> what_to_prune (+ constant tails)
  q0wv_kernel<<<BB*HH, 512, 0, stream>>>(hlnf, Wqkv, wvv);
  srow_kernel<<<dim3(BB, 32), 256, 0, stream>>>(hlnf, wvv, mask, srow);
  sumatt_kernel<<<BB, 1024, 0, stream>>>(srow, attv);
  rank_kernel<<<dim3(BB, 32), 256, 0, stream>>>(attv, dout, offP, offM, offS);

  // 3) QKV projection (768 blocks = 3/CU uniform; depth-2)
  gemm_bt<128,0,3><<<dim3(64, 12), 256, 0, stream>>>(hln_bf, Wqkvt, BB*NN, 1536, 512,
      nullptr, nullptr, nullptr, nullptr, nullptr, Qg, Kg, Vtg);

  // 4) flash attention (XCD-swizzled grid; gl_lds K/V staging)
  attn_kernel<<<512, 256, 0, stream>>>(Qg, Kg, Vtg, mbits, attout);

  // 5) out-proj + bias + residual -> x1b (bf16); 512 blocks = 2/CU, depth-2
  gemm_bt<64,3,3><<<dim3(64, 8), 256, 0, stream>>>(attout, Woutt, BB*NN, 512, 512,
      bout, x, nullptr, nullptr, x1b, nullptr, nullptr, nullptr);

  // 6) LN2 (bf16 in -> bf16 out, wave-per-row)
  ln2_kernel<<<BB*NN/4, 256, 0, stream>>>(x1b, ln2g, ln2b, h2);

  // 7) MLP1 + gelu -> gbuf; 2-buffer 2-phase (32KB -> 4/CU, one round)
  gemm_bt<128,2,2><<<dim3(64, 16), 256, 0, stream>>>(h2, W1t, BB*NN, 2048, 512,
      b1, nullptr, nullptr, nullptr, gbuf, nullptr, nullptr, nullptr);

  // 8) MLP2 + bias + bf16 residual -> final x (f32); depth-2
  gemm_bt<64,4,3><<<dim3(64, 8), 256, 0, stream>>>(gbuf, W2t, BB*NN, 512, 2048,
      b2, nullptr, x1b, dout, nullptr, nullptr, nullptr, nullptr);
}

// Round 14
// 175.592 us; speedup vs baseline: 1.1185x; 1.0043x over previous
//
#include <hip/hip_runtime.h>
#include <hip/hip_bf16.h>
#include <math.h>

// Problem constants
#define BB 8
#define NN 1024
#define DD 512
#define HH 8
#define DHH 64
#define MLPD 2048

typedef __attribute__((ext_vector_type(8))) short short8;
typedef __attribute__((ext_vector_type(4))) float f32x4;

#define MFMA16(a,b,c) __builtin_amdgcn_mfma_f32_16x16x32_bf16(a,b,c,0,0,0)

// 0.125 * log2(e): folded softmax scale (applied to Q at QKV epilogue)
#define QSCALE 0.18033688011112042f
// bit pattern of -1e9f
#define NEGBIG 0xCE6E6B28u

__device__ __forceinline__ short f2bf(float f) {
  union { float f; unsigned u; } x; x.f = f;
  unsigned r = x.u + 0x7FFFu + ((x.u >> 16) & 1u);
  return (short)(r >> 16);
}
__device__ __forceinline__ float bf2f(short s) {
  union { float f; unsigned u; } x;
  x.u = ((unsigned)(unsigned short)s) << 16;
  return x.f;
}

// async global->LDS, 16B per lane; LDS dest must be wave-uniform base
__device__ __forceinline__ void gl_lds16(const short* g, short* l) {
  __builtin_amdgcn_global_load_lds(
      (const __attribute__((address_space(1))) unsigned int*)g,
      (__attribute__((address_space(3))) unsigned int*)l, 16, 0, 0);
}

// fast gelu: tanh form, err <= ~1e-3 abs
__device__ __forceinline__ float gelu_fast(float t) {
  const float u = 0.7978845608028654f * (t + 0.044715f * t * t * t);
  const float e = __builtin_amdgcn_exp2f(u * 2.8853900817779268f); // e^{2u}
  return t - t * __builtin_amdgcn_rcpf(e + 1.0f);                  // t*e/(e+1)
}

// wave-wide fp64 sum (all lanes get result)
__device__ __forceinline__ double wsum64(double v) {
  #pragma unroll
  for (int o = 32; o >= 1; o >>= 1) v += __shfl_xor(v, o, 64);
  return v;
}

// ------- merged prep (latency-optimized):
//   blocks 0..2047     LN1, wave-per-row (4 rows/block)
//   blocks 2048..4095  maskpack via ballot, wave-per-row
//   blocks 4096..7167  weight transpose x4
__global__ __launch_bounds__(256) void prep_kernel(
    const float* __restrict__ x, const float* __restrict__ ln1g,
    const float* __restrict__ ln1b, short* __restrict__ hln_bf,
    float* __restrict__ hlnf,
    const float* __restrict__ mask, unsigned long long* __restrict__ mbits,
    const float* __restrict__ Wqkv, const float* __restrict__ Wout,
    const float* __restrict__ W1,   const float* __restrict__ W2,
    short* __restrict__ Wqkvt, short* __restrict__ Woutt,
    short* __restrict__ W1t,   short* __restrict__ W2t)
{
  const int id = blockIdx.x;
  const int tid = threadIdx.x;
  const int w = tid >> 6, lane = tid & 63;
  if (id < 2048) {
    // ---- LN1: wave per row; lane holds 8 consecutive floats ----
    const int row = id*4 + w;
    const float* xr = x + (size_t)row*DD + lane*8;
    const float4 a = *(const float4*)xr;
    const float4 bv = *(const float4*)(xr + 4);
    double s = ((double)a.x + (double)a.y) + ((double)a.z + (double)a.w)
             + ((double)bv.x + (double)bv.y) + ((double)bv.z + (double)bv.w);
    const double mu = wsum64(s) * (1.0/512.0);
    const double d0 = (double)a.x - mu,  d1 = (double)a.y - mu;
    const double d2 = (double)a.z - mu,  d3 = (double)a.w - mu;
    const double d4 = (double)bv.x - mu, d5 = (double)bv.y - mu;
    const double d6 = (double)bv.z - mu, d7 = (double)bv.w - mu;
    double q = (d0*d0 + d1*d1) + (d2*d2 + d3*d3)
             + (d4*d4 + d5*d5) + (d6*d6 + d7*d7);
    const double var = wsum64(q) * (1.0/512.0);
    const float rs = (float)(1.0 / sqrt(var + 1e-5));
    const float mf = (float)mu;
    const float4 g0 = *(const float4*)(ln1g + lane*8);
    const float4 g1 = *(const float4*)(ln1g + lane*8 + 4);
    const float4 b0 = *(const float4*)(ln1b + lane*8);
    const float4 b1v = *(const float4*)(ln1b + lane*8 + 4);
    float y[8];
    y[0] = (a.x - mf)*rs*g0.x + b0.x;  y[1] = (a.y - mf)*rs*g0.y + b0.y;
    y[2] = (a.z - mf)*rs*g0.z + b0.z;  y[3] = (a.w - mf)*rs*g0.w + b0.w;
    y[4] = (bv.x - mf)*rs*g1.x + b1v.x; y[5] = (bv.y - mf)*rs*g1.y + b1v.y;
    y[6] = (bv.z - mf)*rs*g1.z + b1v.z; y[7] = (bv.w - mf)*rs*g1.w + b1v.w;
    float* of = hlnf + (size_t)row*DD + lane*8;
    *(float4*)of       = (float4){y[0], y[1], y[2], y[3]};
    *(float4*)(of + 4) = (float4){y[4], y[5], y[6], y[7]};
    short8 ob;
    #pragma unroll
    for (int i = 0; i < 8; i++) ob[i] = f2bf(y[i]);
    *(short8*)(hln_bf + (size_t)row*DD + lane*8) = ob;
  } else if (id < 4096) {
    // ---- maskpack via ballot: wave per mask row (1024 floats -> 16 words)
    const int row = (id - 2048)*4 + w;
    const float* p = mask + (size_t)row*NN;
    unsigned long long myword = 0;
    #pragma unroll
    for (int i = 0; i < 16; i++) {
      const float v = p[i*64 + lane];           // coalesced 256B per load
      const unsigned long long m = __ballot(v == 1.0f);
      if (lane == i) myword = m;
    }
    if (lane < 16) mbits[(size_t)row*16 + lane] = myword;
  } else {
    // ---- weight transpose + f32->bf16 ----
    const int id2 = id - 4096;
    const float* W; short* Wt; int K, N, t;
    if (id2 < 768)       { W = Wqkv; Wt = Wqkvt; K = 512;  N = 1536; t = id2; }
    else if (id2 < 1024) { W = Wout; Wt = Woutt; K = 512;  N = 512;  t = id2 - 768; }
    else if (id2 < 2048) { W = W1;   Wt = W1t;   K = 512;  N = 2048; t = id2 - 1024; }
    else                 { W = W2;   Wt = W2t;   K = 2048; N = 512;  t = id2 - 2048; }
    const int nx = N >> 5;
    const int n0 = (t % nx)*32, k0 = (t / nx)*32;
    __shared__ float tile[32][33];
    const int tx = tid & 31, ty = tid >> 5;
    #pragma unroll
    for (int j = 0; j < 4; j++)
      tile[ty + j*8][tx] = W[(size_t)(k0 + ty + j*8)*N + n0 + tx];
    __syncthreads();
    #pragma unroll
    for (int j = 0; j < 4; j++)
      Wt[(size_t)(n0 + ty + j*8)*K + k0 + tx] = f2bf(tile[tx][ty + j*8]);
  }
}

// ---------------- LN2: bf16 in -> bf16 out, wave-per-row -------------------
__global__ __launch_bounds__(256) void ln2_kernel(const short* __restrict__ xb,
    const float* __restrict__ gam, const float* __restrict__ bet,
    short* __restrict__ ob)
{
  const int w = threadIdx.x >> 6, lane = threadIdx.x & 63;
  const int row = blockIdx.x*4 + w;
  const short8 xs = *(const short8*)(xb + (size_t)row*DD + lane*8);
  float v[8];
  #pragma unroll
  for (int i = 0; i < 8; i++) v[i] = bf2f(xs[i]);
  double s = ((double)v[0] + (double)v[1]) + ((double)v[2] + (double)v[3])
           + ((double)v[4] + (double)v[5]) + ((double)v[6] + (double)v[7]);
  const double mu = wsum64(s) * (1.0/512.0);
  double q = 0.0;
  #pragma unroll
  for (int i = 0; i < 8; i++) { const double d = (double)v[i] - mu; q += d*d; }
  const double var = wsum64(q) * (1.0/512.0);
  const float rs = (float)(1.0 / sqrt(var + 1e-5));
  const float mf = (float)mu;
  const float4 g0 = *(const float4*)(gam + lane*8);
  const float4 g1 = *(const float4*)(gam + lane*8 + 4);
  const float4 b0 = *(const float4*)(bet + lane*8);
  const float4 b1v = *(const float4*)(bet + lane*8 + 4);
  const float gg[8] = {g0.x,g0.y,g0.z,g0.w,g1.x,g1.y,g1.z,g1.w};
  const float bb[8] = {b0.x,b0.y,b0.z,b0.w,b1v.x,b1v.y,b1v.z,b1v.w};
  short8 o;
  #pragma unroll
  for (int i = 0; i < 8; i++) o[i] = f2bf((v[i] - mf)*rs*gg[i] + bb[i]);
  *(short8*)(ob + (size_t)row*DD + lane*8) = o;
}

// ---------------- GEMM: A[M][K](bf16) x Bt[N][K](bf16) -> epilogues --------
// 128xBN tile, BK=32, 4 waves (2x2). NBUF=3: depth-2, counted vmcnt.
// NBUF=2: 2-phase, 32KB LDS -> 4+ blocks/CU.
// EPI 0: QKV scatter -> Qg(scaled)/Kg[bh][n][d], Vtg[bh][d][n]   (bf16)
// EPI 2: + bias[col], fast gelu -> bf16 out
// EPI 3: + bias[col] + res_f32[row][col] -> bf16 out   (outproj -> x1b)
// EPI 4: + bias[col] + res_bf16[row][col] -> f32 out   (MLP2 -> dout)
template<int BN, int EPI, int NBUF>
__global__ __launch_bounds__(256) void gemm_bt(
    const short* __restrict__ A, const short* __restrict__ Bt,
    int M, int N, int K,
    const float* __restrict__ bias, const float* __restrict__ res,
    const short* __restrict__ resb,
    float* __restrict__ outf, short* __restrict__ outb,
    short* __restrict__ outQ, short* __restrict__ outK, short* __restrict__ outVt)
{
  constexpr int CH = 8 + BN/16;          // 1KB chunks per K-tile (A:8, B:BN/16)
  constexpr int L  = CH/4;               // gl_lds per wave per tile (4 or 3)
  constexpr int BUFS = (128 + BN)*32;    // shorts per buffer
  __shared__ __align__(16) short lds[NBUF*BUFS];
  const int tid = threadIdx.x;
  const int bm0 = blockIdx.x * 128;
  const int bn0 = blockIdx.y * BN;
  const int lane = tid & 63, wid = tid >> 6;
  const int wm = (wid >> 1) * 64, wn = (wid & 1) * (BN/2);
  const int lr = lane & 15, lg = lane >> 4;
  constexpr int NT = BN/32;              // n-tiles of 16 per wave (4 or 2)

  const short* gsrc[L];
  int loff[L];
  const int scc = (((lane & 3) ^ ((lane >> 3) & 3)))*8;   // pre-swizzled col
  #pragma unroll
  for (int i = 0; i < L; i++) {
    const int c = i*4 + wid;
    const int rr = ((c < 8) ? c : c - 8)*16 + (lane >> 2);
    gsrc[i] = (c < 8) ? (A + (size_t)(bm0 + rr)*K + scc)
                      : (Bt + (size_t)(bn0 + rr)*K + scc);
    loff[i] = c*512;
  }
  const int xs = (lr >> 1) & 3;          // fragment-read slot XOR

  f32x4 acc[4][NT];
  #pragma unroll
  for (int i = 0; i < 4; i++)
    #pragma unroll
    for (int j = 0; j < NT; j++) acc[i][j] = f32x4{0.f,0.f,0.f,0.f};

  const int nsteps = K >> 5;

  auto STAGE = [&](int buf, int t) {
    short* dst = lds + buf*BUFS;
    const int ko = t*32;
    #pragma unroll
    for (int i = 0; i < L; i++)
      gl_lds16(gsrc[i] + ko, dst + loff[i]);
  };
  auto COMPUTE = [&](const short* bufA) {
    const short* bufB = bufA + 4096;
    short8 af[4], bfr[NT];
    #pragma unroll
    for (int mt = 0; mt < 4; mt++)
      af[mt] = *(const short8*)(bufA + (wm + mt*16 + lr)*32 + (lg ^ xs)*8);
    #pragma unroll
    for (int nt = 0; nt < NT; nt++)
      bfr[nt] = *(const short8*)(bufB + (wn + nt*16 + lr)*32 + (lg ^ xs)*8);
    __builtin_amdgcn_s_setprio(1);
    #pragma unroll
    for (int mt = 0; mt < 4; mt++)
      #pragma unroll
      for (int nt = 0; nt < NT; nt++)
        acc[mt][nt] = MFMA16(af[mt], bfr[nt], acc[mt][nt]);
    __builtin_amdgcn_s_setprio(0);
  };

  if constexpr (NBUF == 2) {
    STAGE(0, 0);
    asm volatile("s_waitcnt vmcnt(0)" ::: "memory");
    __builtin_amdgcn_s_barrier();
    int cur = 0;
    #pragma unroll 1
    for (int t = 0; t < nsteps; t++) {
      if (t + 1 < nsteps) STAGE(cur ^ 1, t + 1);
      COMPUTE(lds + cur*BUFS);
      asm volatile("s_waitcnt vmcnt(0)" ::: "memory");
      __builtin_amdgcn_s_barrier();
      cur ^= 1;
    }
  } else {
    STAGE(0, 0);
    STAGE(1, 1);
    int cur = 0;
    #pragma unroll 1
    for (int t = 0; t < nsteps; t++) {
      if (t == nsteps - 1) {
        asm volatile("s_waitcnt vmcnt(0)" ::: "memory");
      } else if constexpr (L == 4) {
        asm volatile("s_waitcnt vmcnt(4)" ::: "memory");
      } else {
        asm volatile("s_waitcnt vmcnt(3)" ::: "memory");
      }
      __builtin_amdgcn_s_barrier();
      if (t + 2 < nsteps) {
        const int bnext = (cur == 0) ? 2 : cur - 1;   // (cur+2)%3
        STAGE(bnext, t + 2);
      }
      COMPUTE(lds + cur*BUFS);
      cur = (cur == 2) ? 0 : cur + 1;
    }
  }

  if (EPI == 0 && bn0 >= 1024) {
    #pragma unroll
    for (int mt = 0; mt < 4; mt++)
      #pragma unroll
      for (int nt = 0; nt < NT; nt++) {
        const int row0 = bm0 + wm + mt*16 + lg*4;
        const int b = row0 >> 10, tok0 = row0 & 1023;
        const int c2 = bn0 + wn + nt*16 + lr - 1024;
        const int h = c2 >> 6, d = c2 & 63;
        unsigned lo2, hi2;
        asm("v_cvt_pk_bf16_f32 %0, %1, %2" : "=v"(lo2)
            : "v"(acc[mt][nt][0]), "v"(acc[mt][nt][1]));
        asm("v_cvt_pk_bf16_f32 %0, %1, %2" : "=v"(hi2)
            : "v"(acc[mt][nt][2]), "v"(acc[mt][nt][3]));
        uint2 pw; pw.x = lo2; pw.y = hi2;
        *(uint2*)(outVt + (((size_t)(b*HH + h))*DHH + d)*NN + tok0) = pw;
      }
    return;
  }

  #pragma unroll
  for (int mt = 0; mt < 4; mt++)
    #pragma unroll
    for (int nt = 0; nt < NT; nt++)
      #pragma unroll
      for (int r = 0; r < 4; r++) {
        const int row = bm0 + wm + mt*16 + lg*4 + r;
        const int col = bn0 + wn + nt*16 + lr;
        const float v = acc[mt][nt][r];
        if (EPI == 0) {
          const int b = row >> 10, tok = row & 1023;
          if (col < 512) {
            const int h = col >> 6, d = col & 63;
            outQ[(((size_t)(b*HH + h))*NN + tok)*DHH + d] = f2bf(v * QSCALE);
          } else {
            const int c2 = col - 512, h = c2 >> 6, d = c2 & 63;
            outK[(((size_t)(b*HH + h))*NN + tok)*DHH + d] = f2bf(v);
          }
        } else if (EPI == 2) {
          outb[(size_t)row*N + col] = f2bf(gelu_fast(v + bias[col]));
        } else if (EPI == 3) {
          outb[(size_t)row*N + col] = f2bf(v + bias[col] + res[(size_t)row*N + col]);
        } else {  // EPI 4
          outf[(size_t)row*N + col] = v + bias[col] + bf2f(resb[(size_t)row*N + col]);
        }
      }
}

// ---------------- flash attention (no-max), swapped QK^T, bit-mask --------
// LDS = 40KB exactly -> 4 blocks/CU (16 waves). Single per-wave P buffer
// [16][64] with unit-XOR swizzle (u_phys = u_log ^ (row&7)); A-set and B-set
// reuse it sequentially (per-wave buffer, program-order LDS deps, no barrier).
__global__ __launch_bounds__(256) void attn_kernel(
    const short* __restrict__ Qg, const short* __restrict__ Kg,
    const short* __restrict__ Vtg, const unsigned long long* __restrict__ mb,
    short* __restrict__ attout)
{
  const int id = blockIdx.x;
  const int bh = (id & 7)*8 + ((id >> 3) & 7);   // same-bh blocks -> same XCD
  const int qb = id >> 6;                        // 0..7
  const int b = bh >> 3, h = bh & 7;
  const int tid = threadIdx.x, lane = tid & 63, w = tid >> 6;
  const int lr = lane & 15, lg = lane >> 4;

  __shared__ __align__(16) short K0[64*64], K1[64*64];
  __shared__ __align__(16) short V0[64*64], V1[64*64];
  __shared__ __align__(16) short Ps[4][16*64];   // single per-wave P buffer

  const int qA = qb*128 + w*32 + lr;
  const int qB = qA + 16;
  short* Psw = &Ps[w][0];

  const size_t qbase = (size_t)bh*NN*DHH;
  const short8 bqA0 = *(const short8*)(Qg + qbase + (size_t)qA*DHH + lg*8);
  const short8 bqA1 = *(const short8*)(Qg + qbase + (size_t)qA*DHH + 32 + lg*8);
  const short8 bqB0 = *(const short8*)(Qg + qbase + (size_t)qB*DHH + lg*8);
  const short8 bqB1 = *(const short8*)(Qg + qbase + (size_t)qB*DHH + 32 + lg*8);

  const unsigned long long* mrowA = mb + ((size_t)b*NN + qA)*16;
  const unsigned long long* mrowB = mb + ((size_t)b*NN + qB)*16;

  const int l8 = lane >> 3;
  const int uu = (lane & 7) ^ l8;
  const short* kgA = Kg + ((size_t)bh*NN + w*16 + l8)*64 + uu*8;
  const short* kgB = kgA + 8*64;
  const short* vgA = Vtg + ((size_t)bh*DHH + w*16 + l8)*NN + uu*8;
  const short* vgB = vgA + 8*NN;
  auto STAGE = [&](short* kb, short* vb, int kc) {
    gl_lds16(kgA + kc*4096, kb + (w*16)*64);
    gl_lds16(kgB + kc*4096, kb + (w*16 + 8)*64);
    gl_lds16(vgA + kc*64,   vb + (w*16)*64);
    gl_lds16(vgB + kc*64,   vb + (w*16 + 8)*64);
  };
  // swizzled unit offsets (shorts) for row lr
  const int xo0 = (lg ^ (lr & 7))*8;
  const int xo1 = ((lg ^ 4) ^ (lr & 7))*8;

  unsigned long long mAc, mBc, mAn, mBn;

  STAGE(K0, V0, 0);
  mAc = mrowA[0]; mBc = mrowB[0];
  asm volatile("s_waitcnt vmcnt(0)" ::: "memory");
  __builtin_amdgcn_s_barrier();

  f32x4 oA[4], oB[4];
  #pragma unroll
  for (int dt = 0; dt < 4; dt++) { oA[dt] = f32x4{0.f,0.f,0.f,0.f}; oB[dt] = f32x4{0.f,0.f,0.f,0.f}; }
  float lsumA = 0.f, lsumB = 0.f;

  // P write address for (nt, set): row lr, logical unit 2nt+(lg>>1), sub (lg&1)*4
#define PS_WADDR(NT_) (Psw + lr*64 + (((2*(NT_) + (lg >> 1)) ^ (lr & 7)))*8 + (lg & 1)*4)

#define ATT_BODY(CK, CV, NK, NV, MAc, MBc, MAn, MBn, KC, LAST)                 \
  {                                                                            \
    if (!(LAST)) {                                                             \
      STAGE(NK, NV, (KC)+1);                                                   \
      MAn = mrowA[(KC)+1]; MBn = mrowB[(KC)+1];                                \
    }                                                                          \
    f32x4 sA[4], sB[4];                                                        \
    {                                                                          \
      const unsigned long long mqA = MAc >> (lg*4);                            \
      const unsigned loA = (unsigned)mqA, hiA = (unsigned)(mqA >> 32);         \
      const unsigned long long mqB = MBc >> (lg*4);                            \
      const unsigned loB = (unsigned)mqB, hiB = (unsigned)(mqB >> 32);         \
      _Pragma("unroll")                                                        \
      for (int nt = 0; nt < 4; nt++) {                                         \
        const unsigned wA = (nt < 2) ? loA : hiA;                              \
        const unsigned wB = (nt < 2) ? loB : hiB;                              \
        const int sh = (nt & 1) * 16;                                          \
        _Pragma("unroll")                                                      \
        for (int rr = 0; rr < 4; rr++) {                                       \
          const unsigned bA = (wA >> (sh + rr)) & 1u;                          \
          const unsigned bB = (wB >> (sh + rr)) & 1u;                          \
          sA[nt][rr] = __uint_as_float((0u - bA) & NEGBIG);                    \
          sB[nt][rr] = __uint_as_float((0u - bB) & NEGBIG);                    \
        }                                                                      \
      }                                                                        \
    }                                                                          \
    __builtin_amdgcn_s_setprio(1);                                             \
    _Pragma("unroll")                                                          \
    for (int nt = 0; nt < 4; nt++) {                                           \
      const short* kr = (CK) + (nt*16 + lr)*64;                                \
      const short8 ak0 = *(const short8*)(kr + xo0);                           \
      const short8 ak1 = *(const short8*)(kr + xo1);                           \
      sA[nt] = MFMA16(ak0, bqA0, sA[nt]);                                      \
      sA[nt] = MFMA16(ak1, bqA1, sA[nt]);                                      \
      sB[nt] = MFMA16(ak0, bqB0, sB[nt]);                                      \
      sB[nt] = MFMA16(ak1, bqB1, sB[nt]);                                      \
    }                                                                          \
    __builtin_amdgcn_s_setprio(0);                                             \
    /* ---- set A: exp -> P(LDS) -> PV ---- */                                 \
    _Pragma("unroll")                                                          \
    for (int nt = 0; nt < 4; nt++) {                                           \
      const float a0 = __builtin_amdgcn_exp2f(sA[nt][0]);                      \
      const float a1 = __builtin_amdgcn_exp2f(sA[nt][1]);                      \
      const float a2 = __builtin_amdgcn_exp2f(sA[nt][2]);                      \
      const float a3 = __builtin_amdgcn_exp2f(sA[nt][3]);                      \
      lsumA += (a0 + a1) + (a2 + a3);                                          \
      unsigned plo, phi;                                                       \
      asm("v_cvt_pk_bf16_f32 %0, %1, %2" : "=v"(plo) : "v"(a0), "v"(a1));      \
      asm("v_cvt_pk_bf16_f32 %0, %1, %2" : "=v"(phi) : "v"(a2), "v"(a3));      \
      uint2 pw; pw.x = plo; pw.y = phi;                                        \
      *(uint2*)PS_WADDR(nt) = pw;                                              \
    }                                                                          \
    {                                                                          \
      const short8 bpA0 = *(const short8*)(Psw + lr*64 + xo0);                 \
      const short8 bpA1 = *(const short8*)(Psw + lr*64 + xo1);                 \
      __builtin_amdgcn_s_setprio(1);                                           \
      _Pragma("unroll")                                                        \
      for (int dt = 0; dt < 4; dt++) {                                         \
        const short* vr = (CV) + (dt*16 + lr)*64;                              \
        const short8 av0 = *(const short8*)(vr + xo0);                         \
        const short8 av1 = *(const short8*)(vr + xo1);                         \
        oA[dt] = MFMA16(av0, bpA0, oA[dt]);                                    \
        oA[dt] = MFMA16(av1, bpA1, oA[dt]);                                    \
      }                                                                        \
      __builtin_amdgcn_s_setprio(0);                                           \
    }                                                                          \
    /* ---- set B: exp -> P(LDS, same buffer) -> PV ---- */                    \
    _Pragma("unroll")                                                          \
    for (int nt = 0; nt < 4; nt++) {                                           \
      const float c0 = __builtin_amdgcn_exp2f(sB[nt][0]);                      \
      const float c1 = __builtin_amdgcn_exp2f(sB[nt][1]);                      \
      const float c2 = __builtin_amdgcn_exp2f(sB[nt][2]);                      \
      const float c3 = __builtin_amdgcn_exp2f(sB[nt][3]);                      \
      lsumB += (c0 + c1) + (c2 + c3);                                          \
      unsigned qlo, qhi;                                                       \
      asm("v_cvt_pk_bf16_f32 %0, %1, %2" : "=v"(qlo) : "v"(c0), "v"(c1));      \
      asm("v_cvt_pk_bf16_f32 %0, %1, %2" : "=v"(qhi) : "v"(c2), "v"(c3));      \
      uint2 qw; qw.x = qlo; qw.y = qhi;                                        \
      *(uint2*)PS_WADDR(nt) = qw;                                              \
    }                                                                          \
    {                                                                          \
      const short8 bpB0 = *(const short8*)(Psw + lr*64 + xo0);                 \
      const short8 bpB1 = *(const short8*)(Psw + lr*64 + xo1);                 \
      __builtin_amdgcn_s_setprio(1);                                           \
      _Pragma("unroll")                                                        \
      for (int dt = 0; dt < 4; dt++) {                                         \
        const short* vr = (CV) + (dt*16 + lr)*64;                              \
        const short8 av0 = *(const short8*)(vr + xo0);                         \
        const short8 av1 = *(const short8*)(vr + xo1);                         \
        oB[dt] = MFMA16(av0, bpB0, oB[dt]);                                    \
        oB[dt] = MFMA16(av1, bpB1, oB[dt]);                                    \
      }                                                                        \
      __builtin_amdgcn_s_setprio(0);                                           \
    }                                                                          \
    if (!(LAST)) {                                                             \
      asm volatile("s_waitcnt vmcnt(0)" ::: "memory");                         \
      __builtin_amdgcn_s_barrier();                                            \
      MAc = MAn; MBc = MBn;                                                    \
    }                                                                          \
  }

  #pragma unroll 1
  for (int kc = 0; kc < 16; kc += 2) {
    ATT_BODY(K0, V0, K1, V1, mAc, mBc, mAn, mBn, kc, false)
    ATT_BODY(K1, V1, K0, V0, mAc, mBc, mAn, mBn, kc+1, (kc+1) == 15)
  }
#undef ATT_BODY

  lsumA += __shfl_xor(lsumA, 16, 64);
  lsumA += __shfl_xor(lsumA, 32, 64);
  lsumB += __shfl_xor(lsumB, 16, 64);
  lsumB += __shfl_xor(lsumB, 32, 64);
  const float linvA = 1.0f / lsumA;
  const float linvB = 1.0f / lsumB;

  // O^T -> per-wave LDS transpose (swizzled), coalesced stores; A then B
  #pragma unroll
  for (int dt = 0; dt < 4; dt++) {
    unsigned w0, w1;
    const float a0 = oA[dt][0]*linvA, a1 = oA[dt][1]*linvA;
    const float a2 = oA[dt][2]*linvA, a3 = oA[dt][3]*linvA;
    asm("v_cvt_pk_bf16_f32 %0, %1, %2" : "=v"(w0) : "v"(a0), "v"(a1));
    asm("v_cvt_pk_bf16_f32 %0, %1, %2" : "=v"(w1) : "v"(a2), "v"(a3));
    uint2 ow; ow.x = w0; ow.y = w1;
    *(uint2*)PS_WADDR(dt) = ow;
  }
  #pragma unroll
  for (int rep = 0; rep < 2; rep++) {
    const int c = lane + rep*64;
    const int row = c >> 3, off = c & 7;
    const uint4 ovA = *(const uint4*)(Psw + row*64 + (off ^ (row & 7))*8);
    *(uint4*)(attout + ((size_t)b*NN + qb*128 + w*32 + row)*DD + h*DHH + off*8) = ovA;
  }
  #pragma unroll
  for (int dt = 0; dt < 4; dt++) {
    unsigned w2, w3;
    const float c0 = oB[dt][0]*linvB, c1 = oB[dt][1]*linvB;
    const float c2 = oB[dt][2]*linvB, c3 = oB[dt][3]*linvB;
    asm("v_cvt_pk_bf16_f32 %0, %1, %2" : "=v"(w2) : "v"(c0), "v"(c1));
    asm("v_cvt_pk_bf16_f32 %0, %1, %2" : "=v"(w3) : "v"(c2), "v"(c3));
    uint2 ow2; ow2.x = w2; ow2.y = w3;
    *(uint2*)PS_WADDR(dt) = ow2;
  }
  #pragma unroll
  for (int rep = 0; rep < 2; rep++) {
    const int c = lane + rep*64;
    const int row = c >> 3, off = c & 7;
    const uint4 ovB = *(const uint4*)(Psw + row*64 + (off ^ (row & 7))*8);
    *(uint4*)(attout + ((size_t)b*NN + qb*128 + w*32 + 16 + row)*DD + h*DHH + off*8) = ovB;
  }
#undef PS_WADDR
}

// ---------------- exact score path (fp64) for what_to_prune ----------------
__global__ __launch_bounds__(512) void q0wv_kernel(const float* __restrict__ hlnf,
    const float* __restrict__ Wqkv, double* __restrict__ wv)
{
  const int bh = blockIdx.x, b = bh >> 3, h = bh & 7;
  __shared__ double red[512];
  __shared__ double q0s[64];
  {
    const int d = threadIdx.x & 63, cg = threadIdx.x >> 6;
    double acc = 0.0;
    #pragma unroll 8
    for (int c = cg*64; c < cg*64 + 64; c++)
      acc += (double)hlnf[(size_t)b*NN*DD + c] * (double)Wqkv[(size_t)c*1536 + h*64 + d];
    red[threadIdx.x] = acc;
    __syncthreads();
    if (threadIdx.x < 64) {
      double s = 0.0;
      #pragma unroll
      for (int g = 0; g < 8; g++) s += red[g*64 + d];
      q0s[d] = s;
    }
    __syncthreads();
  }
  const int c = threadIdx.x;
  const float4* wp = (const float4*)(Wqkv + (size_t)c*1536 + 512 + h*64);
  double acc = 0.0;
  #pragma unroll
  for (int dv = 0; dv < 16; dv++) {
    const float4 wq = wp[dv];
    acc += q0s[dv*4+0]*(double)wq.x + q0s[dv*4+1]*(double)wq.y
         + q0s[dv*4+2]*(double)wq.z + q0s[dv*4+3]*(double)wq.w;
  }
  wv[(size_t)bh*512 + c] = acc;
}

__global__ __launch_bounds__(256) void srow_kernel(const float* __restrict__ hlnf,
    const double* __restrict__ wv, const float* __restrict__ mask,
    double* __restrict__ srow)
{
  const int b = blockIdx.x, jc = blockIdx.y;
  const int jl = threadIdx.x >> 3;
  const int cg = threadIdx.x & 7;
  const int j  = jc*32 + jl;
  __shared__ double lw[8*512];
  __shared__ double red[32][8][9];
  for (int i = threadIdx.x; i < 4096; i += 256) lw[i] = wv[(size_t)b*4096 + i];
  __syncthreads();
  double acc[8] = {0,0,0,0,0,0,0,0};
  const float* xr = hlnf + ((size_t)b*NN + j)*DD;
  #pragma unroll
  for (int i = 0; i < 16; i++) {
    const int c = cg*4 + i*32;
    const float4 xv4 = *(const float4*)(xr + c);
    #pragma unroll
    for (int h = 0; h < 8; h++) {
      const double* lwc = lw + h*512 + c;
      acc[h] += (double)xv4.x*lwc[0] + (double)xv4.y*lwc[1]
              + (double)xv4.z*lwc[2] + (double)xv4.w*lwc[3];
    }
  }
  #pragma unroll
  for (int h = 0; h < 8; h++) red[jl][cg][h] = acc[h];
  __syncthreads();
  const int j2 = threadIdx.x >> 3, h2 = threadIdx.x & 7;
  double s = 0.0;
  #pragma unroll
  for (int g = 0; g < 8; g++) s += red[j2][g][h2];
  s *= 0.125;
  const float mval = mask[(size_t)b*NN*NN + jc*32 + j2];
  if (mval == 1.0f) s = -1e10;
  srow[((size_t)b*8 + h2)*NN + jc*32 + j2] = s;
}

// fused denominator + att (no max subtraction; fp64 exp safe, masked -> 0)
__global__ __launch_bounds__(1024) void sumatt_kernel(const double* __restrict__ srow,
    double* __restrict__ attv)
{
  const int b = blockIdx.x;
  const int t = threadIdx.x;
  __shared__ double e[8][1024];
  __shared__ double red[1024];
  __shared__ double sinv[8];
  const int h = t >> 7, j0 = t & 127;
  double ps = 0.0;
  #pragma unroll
  for (int i = 0; i < 8; i++) {
    const int j = j0 + i*128;
    const double v = exp(srow[((size_t)b*8 + h)*NN + j]);
    e[h][j] = v;
    ps += v;
  }
  red[t] = ps;
  __syncthreads();
  #pragma unroll
  for (int off = 64; off >= 1; off >>= 1) {
    if (j0 < off) red[t] += red[t + off];
    __syncthreads();
  }
  if (j0 == 0) sinv[h] = 1.0 / red[t];
  __syncthreads();
  double s = 0.0;
  #pragma unroll
  for (int hh = 0; hh < 8; hh++) s += e[hh][t] * sinv[hh];
  attv[b*NN + t] = (t == 0) ? -INFINITY : s * 0.125;
}

// rank-by-counting (exact stable-argsort semantics), parallelized
__global__ __launch_bounds__(256) void rank_kernel(const double* __restrict__ attv,
    float* __restrict__ dout, int offP, int offM, int offS)
{
  const int b = blockIdx.x, jc = blockIdx.y;
  const int t = threadIdx.x;
  __shared__ double a[1024];
  __shared__ int red[32][8];
  #pragma unroll
  for (int rep = 0; rep < 4; rep++)
    a[rep*256 + t] = attv[b*NN + rep*256 + t];
  __syncthreads();
  const int jl = t >> 3, kg = t & 7;
  const int j = jc*32 + jl;
  const double aj = a[j];
  int r = 0;
  #pragma unroll 8
  for (int i = 0; i < 128; i++) {
    const int idx = kg*128 + ((i + kg*2) & 127);
    const double ak = a[idx];
    r += ((ak > aj) || (ak == aj && idx < j)) ? 1 : 0;
  }
  red[jl][kg] = r;
  __syncthreads();
  if (t < 32) {
    int rr = 0;
    #pragma unroll
    for (int g = 0; g < 8; g++) rr += red[t][g];
    const int jj = jc*32 + t;
    if (rr >= 959 && rr <= 1022) dout[offP + b*64 + (rr - 959)] = (float)jj;
  }
  if (b == 0 && jc == 0) {
    if (t < 8)   dout[offM + t] = -1.0f;
    if (t < 128) dout[offS + t] = 0.0f;
  }
}

// ---------------------------------------------------------------------------
extern "C" void kernel_launch(void* const* d_in, const int* in_sizes, int n_in,
                              void* d_out, int out_size, void* d_ws, size_t ws_size,
                              hipStream_t stream) {
  (void)in_sizes; (void)n_in; (void)out_size; (void)ws_size;
  const float* x     = (const float*)d_in[0];
  const float* mask  = (const float*)d_in[1];
  const float* Wqkv  = (const float*)d_in[2];
  const float* Wout  = (const float*)d_in[3];
  const float* bout  = (const float*)d_in[4];
  const float* ln1g  = (const float*)d_in[5];
  const float* ln1b  = (const float*)d_in[6];
  const float* ln2g  = (const float*)d_in[7];
  const float* ln2b  = (const float*)d_in[8];
  const float* W1    = (const float*)d_in[9];
  const float* b1    = (const float*)d_in[10];
  const float* W2    = (const float*)d_in[11];
  const float* b2    = (const float*)d_in[12];
  float* dout = (float*)d_out;

  const size_t MB = 1ull << 20;
  char* ws = (char*)d_ws;
  short*  hln_bf = (short*)(ws + 0);           // 8 MB
  float*  hlnf   = (float*)(ws + 8*MB);        // 16 MB
  short*  Qg     = (short*)(ws + 24*MB);       // 8 MB
  short*  Kg     = (short*)(ws + 32*MB);       // 8 MB
  short*  Vtg    = (short*)(ws + 40*MB);       // 8 MB
  unsigned long long* mbits = (unsigned long long*)(ws + 48*MB); // 1 MB
  short*  Wqkvt  = (short*)(ws + 49*MB);       // 1.5 MB
  short*  Woutt  = (short*)(ws + 51*MB);       // 0.5 MB
  short*  W1t    = (short*)(ws + 52*MB);       // 2 MB
  short*  W2t    = (short*)(ws + 54*MB);       // 2 MB
  double* wvv    = (double*)(ws + 56*MB + 256*1024);   // 256 KB
  double* srow   = (double*)(ws + 57*MB);              // 512 KB
  double* attv   = (double*)(ws + 59*MB);              // 64 KB
  short*  attout = (short*)(ws + 60*MB);       // 8 MB
  short*  x1b    = (short*)(ws + 68*MB);       // 4 MB (bf16)
  short*  h2     = (short*)(ws + 84*MB);       // 8 MB
  short*  gbuf   = (short*)(ws + 0);           // 32 MB, reuses [0,32) (dead by MLP1)

  const int offP = BB*NN*DD;          // 4194304
  const int offM = offP + BB*64;      // 4194816
  const int offS = offM + BB;         // 4194824

  // 1) merged prep: LN1 (wave/row) + maskpack (ballot) + weight transposes
  prep_kernel<<<7168, 256, 0, stream>>>(x, ln1g, ln1b, hln_bf, hlnf,
      mask, mbits, Wqkv, Wout, W1, W2, Wqkvt, Woutt, W1t, W2t);

  // 2) exact fp64 score path -> what_to_prune (+ constant tails)
  q0wv_kernel<<<BB*HH, 512, 0, stream>>>(hlnf, Wqkv, wvv);
  srow_kernel<<<dim3(BB, 32), 256, 0, stream>>>(hlnf, wvv, mask, srow);
  sumatt_kernel<<<BB, 1024, 0, stream>>>(srow, attv);
  rank_kernel<<<dim3(BB, 32), 256, 0, stream>>>(attv, dout, offP, offM, offS);

  // 3) QKV projection (768 blocks = 3/CU uniform; depth-2)
  gemm_bt<128,0,3><<<dim3(64, 12), 256, 0, stream>>>(hln_bf, Wqkvt, BB*NN, 1536, 512,
      nullptr, nullptr, nullptr, nullptr, nullptr, Qg, Kg, Vtg);

  // 4) flash attention (XCD-swizzled grid; 40KB LDS -> 4 blocks/CU)
  attn_kernel<<<512, 256, 0, stream>>>(Qg, Kg, Vtg, mbits, attout);

  // 5) out-proj + bias + residual -> x1b (bf16); 512 blocks = 2/CU, depth-2
  gemm_bt<64,3,3><<<dim3(64, 8), 256, 0, stream>>>(attout, Woutt, BB*NN, 512, 512,
      bout, x, nullptr, nullptr, x1b, nullptr, nullptr, nullptr);

  // 6) LN2 (bf16 in -> bf16 out, wave-per-row)
  ln2_kernel<<<BB*NN/4, 256, 0, stream>>>(x1b, ln2g, ln2b, h2);

  // 7) MLP1 + gelu -> gbuf; 2-buffer 2-phase (32KB -> 4/CU, one round)
  gemm_bt<128,2,2><<<dim3(64, 16), 256, 0, stream>>>(h2, W1t, BB*NN, 2048, 512,
      b1, nullptr, nullptr, nullptr, gbuf, nullptr, nullptr, nullptr);

  // 8) MLP2 + bias + bf16 residual -> final x (f32); depth-2
  gemm_bt<64,4,3><<<dim3(64, 8), 256, 0, stream>>>(gbuf, W2t, BB*NN, 512, 2048,
      b2, nullptr, x1b, dout, nullptr, nullptr, nullptr, nullptr);
}